// Round 16
// baseline (904.051 us; speedup 1.0000x reference)
//
#include <hip/hip_runtime.h>
#include <cstdint>
#include <cstddef>

#define HD 128
#define NLAYER 4
#define EINDIM 385

typedef _Float16 f16x8 __attribute__((ext_vector_type(8)));
typedef _Float16 f16x4 __attribute__((ext_vector_type(4)));
typedef float f32x4 __attribute__((ext_vector_type(4)));

// fast silu: v_mul+v_exp+v_add+v_rcp+v_mul (no IEEE divide)
__device__ __forceinline__ float silu_f(float x) {
    float e = __expf(-x);
    return x * __builtin_amdgcn_rcpf(1.f + e);
}

// LDS-only barrier: does NOT drain vmcnt -> prefetch loads stay in flight
__device__ __forceinline__ void lds_barrier() {
    asm volatile("s_waitcnt lgkmcnt(0)" ::: "memory");
    __builtin_amdgcn_s_barrier();
}

// ---------------- init: lam_vec + folded edge bias c1 (fp32 + fp16) ----------------
__global__ __launch_bounds__(128) void k_init(const float* __restrict__ lam_p,
                                              const float* __restrict__ lam_w,
                                              const float* __restrict__ lam_b,
                                              const float* __restrict__ edge_w1,
                                              const float* __restrict__ edge_b1,
                                              float* __restrict__ lam_vec,
                                              float* __restrict__ c1,
                                              _Float16* __restrict__ c1h) {
    __shared__ float sl[HD];
    const int j = threadIdx.x;   // 0..127
    const int l = blockIdx.x;    // 0..NLAYER-1
    float lam = lam_p[0];
    float v = lam * lam_w[j] + lam_b[j];
    sl[j] = v;
    if (l == 0) lam_vec[j] = v;
    __syncthreads();
    float acc = edge_b1[l * HD + j];
    const float* w = edge_w1 + ((size_t)l * EINDIM + 257) * HD + j;
#pragma unroll 8
    for (int k = 0; k < HD; k++) acc = fmaf(sl[k], w[(size_t)k * HD], acc);
    c1[l * HD + j] = acc;
    c1h[l * HD + j] = (_Float16)acc;
}

// ---------------- prep: transpose weights to [col][k] fp16, extract dist row ----------------
__global__ void k_prep(const float* __restrict__ ew1, const float* __restrict__ ew2,
                       const float* __restrict__ nw1, const float* __restrict__ nw2,
                       _Float16* __restrict__ W1te, _Float16* __restrict__ W2te,
                       _Float16* __restrict__ W1tn, _Float16* __restrict__ W2tn,
                       float* __restrict__ wd, _Float16* __restrict__ wdh) {
    int t = blockIdx.x * 256 + threadIdx.x;
    if (t < NLAYER * 128 * 256) {
        int l = t >> 15, r = t & 32767, j = r >> 8, k = r & 255;
        W1te[t] = (_Float16)ew1[((size_t)l * EINDIM + k) * HD + j];
        return;
    }
    t -= NLAYER * 128 * 256;
    if (t < NLAYER * 128 * 256) {
        int l = t >> 15, r = t & 32767, j = r >> 8, k = r & 255;
        W1tn[t] = (_Float16)nw1[((size_t)l * 256 + k) * HD + j];
        return;
    }
    t -= NLAYER * 128 * 256;
    if (t < NLAYER * 128 * 128) {
        int l = t >> 14, r = t & 16383, j = r >> 7, k = r & 127;
        W2te[t] = (_Float16)ew2[((size_t)l * 128 + k) * HD + j];
        return;
    }
    t -= NLAYER * 128 * 128;
    if (t < NLAYER * 128 * 128) {
        int l = t >> 14, r = t & 16383, j = r >> 7, k = r & 127;
        W2tn[t] = (_Float16)nw2[((size_t)l * 128 + k) * HD + j];
        return;
    }
    t -= NLAYER * 128 * 128;
    if (t < NLAYER * 128) {
        int l = t >> 7, j = t & 127;
        float v = ew1[((size_t)l * EINDIM + 256) * HD + j];
        wd[t] = v;
        wdh[t] = (_Float16)v;
    }
}

// ---------------- h0 = atom_embed[z] + lam_vec (fp32 + fp16 copies) ----------------
__global__ void k_embed(const int* __restrict__ z,
                        const float* __restrict__ atom_embed,
                        const float* __restrict__ lam_vec,
                        float* __restrict__ h, _Float16* __restrict__ hh, int n4) {
    int i = blockIdx.x * 256 + threadIdx.x;
    if (i >= n4) return;
    int n = i >> 5, q = i & 31;
    int a = z[n];
    float4 e = *(const float4*)&atom_embed[(size_t)a * HD + q * 4];
    float4 lv = *(const float4*)&lam_vec[q * 4];
    e.x += lv.x; e.y += lv.y; e.z += lv.z; e.w += lv.w;
    *(float4*)&h[(size_t)n * HD + q * 4] = e;
    f16x4 hv;
    hv[0] = (_Float16)e.x; hv[1] = (_Float16)e.y;
    hv[2] = (_Float16)e.z; hv[3] = (_Float16)e.w;
    *(f16x4*)&hh[(size_t)n * HD + q * 4] = hv;
}

// ---------------- generic zero ----------------
__global__ void k_zero(float4* __restrict__ p, int n4) {
    for (int i = blockIdx.x * 256 + threadIdx.x; i < n4; i += gridDim.x * 256)
        p[i] = make_float4(0.f, 0.f, 0.f, 0.f);
}

// ---------------- counting sort: histogram ----------------
__global__ void k_hist(const int* __restrict__ ei, int* __restrict__ deg, int E) {
    int e = blockIdx.x * 256 + threadIdx.x;
    if (e < E) atomicAdd(&deg[ei[e]], 1);
}

// ---------------- counting sort: single-block scan deg -> cursor ----------------
__global__ __launch_bounds__(1024) void k_scan(const int* __restrict__ deg,
                                               int* __restrict__ cursor, int N) {
    __shared__ int part[1024];
    int t = threadIdx.x;
    int chunk = (N + 1023) >> 10;
    int s0 = t * chunk, s1 = s0 + chunk;
    if (s1 > N) s1 = N;
    int s = 0;
    for (int i = s0; i < s1; i++) s += deg[i];
    part[t] = s;
    __syncthreads();
    for (int d = 1; d < 1024; d <<= 1) {
        int v = (t >= d) ? part[t - d] : 0;
        __syncthreads();
        part[t] += v;
        __syncthreads();
    }
    int base = (t == 0) ? 0 : part[t - 1];
    for (int i = s0; i < s1; i++) {
        cursor[i] = base;
        base += deg[i];
    }
}

// ---------------- counting sort: scatter permutation ----------------
__global__ void k_scatter(const int* __restrict__ ei, int* __restrict__ cursor,
                          int* __restrict__ perm, int E) {
    int e = blockIdx.x * 256 + threadIdx.x;
    if (e < E) {
        int p = atomicAdd(&cursor[ei[e]], 1);
        perm[p] = e;
    }
}

// ---------------- apply perm: rowS/colS/distS (sorted by row) ----------------
__global__ void k_apply(const int* __restrict__ perm, const int* __restrict__ ei,
                        const float* __restrict__ pos,
                        int* __restrict__ rowS, int* __restrict__ colS,
                        float* __restrict__ distS, int E, int Epad) {
    int i = blockIdx.x * 256 + threadIdx.x;
    if (i >= Epad) return;
    if (i < E) {
        int e = perm[i];
        int r = ei[e], c = ei[E + e];
        rowS[i] = r; colS[i] = c;
        float dx = pos[r * 3 + 0] - pos[c * 3 + 0];
        float dy = pos[r * 3 + 1] - pos[c * 3 + 1];
        float dz = pos[r * 3 + 2] - pos[c * 3 + 2];
        distS[i] = sqrtf(dx * dx + dy * dy + dz * dz + 1e-8f);
    } else {
        rowS[i] = -1; colS[i] = 0; distS[i] = 0.f;
    }
}

// ---------------- per-tile boundary masks: bit i = rowS[i] != rowS[i+1] ----------------
__global__ void k_mask(const int* __restrict__ rowS,
                       unsigned long long* __restrict__ maskBuf, int Epad) {
    int i = blockIdx.x * 256 + threadIdx.x;
    if (i >= Epad) return;   // Epad multiple of 64: whole waves uniform
    bool pred = (i + 1 >= Epad) ? true : (rowS[i] != rowS[i + 1]);
    unsigned long long m = __ballot(pred);
    if ((i & 63) == 0) maskBuf[i >> 6] = m;
}

// =======================================================================
// per-node edge-message precompute: P = h @ W1a, Q = h @ W1b (fp16 out).
// 512 threads / 8 waves x 16 cols; dense 64-row tiles; K=128 each.
// =======================================================================
__global__ __launch_bounds__(512, 4) void k_pq(
    const _Float16* __restrict__ hh, int N,
    const _Float16* __restrict__ W1t,   // [128][256] (k<128: h_row part, k>=128: h_col part)
    _Float16* __restrict__ Ph, _Float16* __restrict__ Qh) {
    __shared__ __align__(16) _Float16 shH[64 * 136];
    const int tid = threadIdx.x;
    const int w = tid >> 6, l = tid & 63;
    const int lg = l >> 4, lr = l & 15;
    const int col = w * 16 + lr;

    f16x8 w1a[4], w1b[4];
#pragma unroll
    for (int s = 0; s < 4; s++) {
        w1a[s] = *(const f16x8*)(W1t + (size_t)col * 256 + s * 32 + lg * 8);
        w1b[s] = *(const f16x8*)(W1t + (size_t)col * 256 + 128 + s * 32 + lg * 8);
    }
    const int n0 = blockIdx.x * 64;
#pragma unroll
    for (int it = 0; it < 2; it++) {
        int flat = tid + it * 512;
        int e = flat >> 4, c = flat & 15;
        int n = n0 + e;
        f16x8 v = {};
        if (n < N) v = *(const f16x8*)(hh + (size_t)n * HD + c * 8);
        *(f16x8*)&shH[e * 136 + c * 8] = v;
    }
    __syncthreads();

    f32x4 aP[4], aQ[4];
#pragma unroll
    for (int rf = 0; rf < 4; rf++) { aP[rf] = (f32x4){0,0,0,0}; aQ[rf] = (f32x4){0,0,0,0}; }
#pragma unroll
    for (int s = 0; s < 4; s++) {
#pragma unroll
        for (int rf = 0; rf < 4; rf++) {
            f16x8 a = *(const f16x8*)&shH[(rf * 16 + lr) * 136 + s * 32 + lg * 8];
            aP[rf] = __builtin_amdgcn_mfma_f32_16x16x32_f16(a, w1a[s], aP[rf], 0, 0, 0);
            aQ[rf] = __builtin_amdgcn_mfma_f32_16x16x32_f16(a, w1b[s], aQ[rf], 0, 0, 0);
        }
    }
#pragma unroll
    for (int rf = 0; rf < 4; rf++) {
#pragma unroll
        for (int r = 0; r < 4; r++) {
            int n = n0 + rf * 16 + lg * 4 + r;
            if (n < N) {
                Ph[(size_t)n * HD + col] = (_Float16)aP[rf][r];
                Qh[(size_t)n * HD + col] = (_Float16)aQ[rf][r];
            }
        }
    }
}

// =======================================================================
// edge kernel v2: NO edge GEMM1.  m1 = silu(P[row]+Q[col]+dist*wd+c1)
// computed during staging (packed-fp16 add chain, fp32 silu); then
// GEMM2 (W2 in 16 regs/thread), ep2, mask-driven segmented reduce.
// 512 threads; (512,6): 3 blocks/CU (reg footprint ~68 <= 85 budget).
// =======================================================================
__global__ __launch_bounds__(512, 6) void k_edge_mfma(
    const _Float16* __restrict__ Ph, const _Float16* __restrict__ Qh,
    const int* __restrict__ rowS, const int* __restrict__ colS,
    const float* __restrict__ distS,
    const unsigned long long* __restrict__ maskBuf,
    int Epad, int ntiles, int tpb,
    const _Float16* __restrict__ W2t,   // [128][128] fp16
    const _Float16* __restrict__ wdh, const _Float16* __restrict__ c1h,
    const float* __restrict__ b2,
    float* __restrict__ agg) {
    __shared__ __align__(16) _Float16 shM[64 * 136];   // m1, then final m2 (fp16)
    __shared__ int shRow2[2][64];

    const int tid = threadIdx.x;
    const int w = tid >> 6, l = tid & 63;
    const int lg = l >> 4, lr = l & 15;
    const int col = w * 16 + lr;
    const int cc = tid & 15;              // staging chunk (cols cc*8..cc*8+7)

    f16x8 w2f[4];
#pragma unroll
    for (int s = 0; s < 4; s++)
        w2f[s] = *(const f16x8*)(W2t + (size_t)col * 128 + s * 32 + lg * 8);
    const f16x8 wd8 = *(const f16x8*)(wdh + cc * 8);
    const f16x8 c18 = *(const f16x8*)(c1h + cc * 8);
    const float b2v = b2[col];

    const int t0 = blockIdx.x * tpb;
    int t1 = t0 + tpb; if (t1 > ntiles) t1 = ntiles;
    if (t0 >= t1) return;   // uniform per block

    // prefetch pipeline registers
    f16x8 vP[2], vQ[2];
    float dva[2];
    int rv = -1;

    // ---- prologue: gather tile t0 ----
    {
        const int e0 = t0 * 64;
        if (tid < 64) rv = rowS[e0 + tid];
#pragma unroll
        for (int it = 0; it < 2; it++) {
            int e = (tid + it * 512) >> 4;
            int r_ = rowS[e0 + e], q_ = colS[e0 + e];
            if (r_ < 0) r_ = 0;
            vP[it] = *(const f16x8*)(Ph + (size_t)r_ * HD + cc * 8);
            vQ[it] = *(const f16x8*)(Qh + (size_t)q_ * HD + cc * 8);
            dva[it] = distS[e0 + e];
        }
    }

    for (int t = t0; t < t1; t++) {
        const int pb = t & 1;
        const unsigned long long bmCur = maskBuf[t];
        const unsigned long long bmPrev = (t > 0) ? maskBuf[t - 1] : ~0ull;

        lds_barrier();                 // B0: prev tile's segreduce reads done

        // stage: m1 = silu(P[row]+Q[col]+dist*wd+c1) -> shM
        // add-chain in packed fp16 (v_pk_add/pk_fma); silu in fp32
#pragma unroll
        for (int it = 0; it < 2; it++) {
            int e = (tid + it * 512) >> 4;
            _Float16 dh = (_Float16)dva[it];
            f16x8 x = vP[it] + vQ[it] + dh * wd8 + c18;
            f16x8 mv;
#pragma unroll
            for (int j = 0; j < 8; j++)
                mv[j] = (_Float16)silu_f((float)x[j]);
            *(f16x8*)&shM[e * 136 + cc * 8] = mv;
        }
        if (tid < 64) shRow2[pb][tid] = rv;

        // prefetch tile t+1 (loads fly across the lds-only barriers)
        {
            int tn = t + 1; if (tn > ntiles - 1) tn = ntiles - 1;
            const int e0n = tn * 64;
#pragma unroll
            for (int it = 0; it < 2; it++) {
                int e = (tid + it * 512) >> 4;
                int r_ = rowS[e0n + e], q_ = colS[e0n + e];
                if (r_ < 0) r_ = 0;
                vP[it] = *(const f16x8*)(Ph + (size_t)r_ * HD + cc * 8);
                vQ[it] = *(const f16x8*)(Qh + (size_t)q_ * HD + cc * 8);
                dva[it] = distS[e0n + e];
            }
            if (tid < 64) rv = rowS[e0n + tid];
        }

        lds_barrier();                 // B1: shM(t) + shRow visible

        f32x4 acc[4];
#pragma unroll
        for (int rf = 0; rf < 4; rf++) acc[rf] = (f32x4){0.f, 0.f, 0.f, 0.f};

        // GEMM2: K=128, barrier-free (B in registers)
#pragma unroll
        for (int s = 0; s < 4; s++) {
#pragma unroll
            for (int rf = 0; rf < 4; rf++) {
                f16x8 a = *(const f16x8*)&shM[(rf * 16 + lr) * 136 + s * 32 + lg * 8];
                acc[rf] = __builtin_amdgcn_mfma_f32_16x16x32_f16(a, w2f[s], acc[rf], 0, 0, 0);
            }
        }
        lds_barrier();                 // B4: all GEMM2 reads done before overwrite

        // ep2: silu -> shM (fp16, reuse)
#pragma unroll
        for (int rf = 0; rf < 4; rf++) {
#pragma unroll
            for (int r = 0; r < 4; r++) {
                int row = rf * 16 + lg * 4 + r;
                shM[row * 136 + col] = (_Float16)silu_f(acc[rf][r] + b2v);
            }
        }
        lds_barrier();                 // B5: final m visible

        // mask-driven segmented reduction: 4 quarter-tiles x 128 cols
        {
            const int scol = tid & 127, quarter = tid >> 7;   // 0..3
            const int i0 = quarter << 4;                      // 16 rows each
            const unsigned int mh = (unsigned int)(bmCur >> i0) & 0xFFFFu;
            bool open = (quarter == 0) ? !((bmPrev >> 63) & 1ull)
                                       : !((bmCur >> (i0 - 1)) & 1ull);
            float s = 0.f;
#pragma unroll
            for (int ib = 0; ib < 4; ib++) {
                const int i = i0 + ib * 4;
                float v0 = (float)shM[(i + 0) * 136 + scol];
                float v1 = (float)shM[(i + 1) * 136 + scol];
                float v2 = (float)shM[(i + 2) * 136 + scol];
                float v3 = (float)shM[(i + 3) * 136 + scol];
#pragma unroll
                for (int q = 0; q < 4; q++) {
                    s += (q == 0) ? v0 : (q == 1) ? v1 : (q == 2) ? v2 : v3;
                    if (mh & (1u << (ib * 4 + q))) {
                        int rc = shRow2[pb][i + q];
                        if (rc >= 0) {
                            if (open) atomicAdd(&agg[(size_t)rc * HD + scol], s);
                            else      agg[(size_t)rc * HD + scol] = s;
                        }
                        s = 0.f;
                        open = false;
                    }
                }
            }
            if (!((mh >> 15) & 1u)) {
                int rc = shRow2[pb][i0 + 15];
                if (rc >= 0) atomicAdd(&agg[(size_t)rc * HD + scol], s);
            }
        }
    }
}

// =======================================================================
// node MLP via MFMA fp16 + fused residual + LayerNorm.  (256,3).
// Staging also ZEROES agg in place (exclusive per tile).  [unchanged]
// =======================================================================
__global__ __launch_bounds__(256, 3) void k_node_mfma(
    const _Float16* __restrict__ hh_in, float* __restrict__ agg, int N,
    int ntiles, int tpb,
    const _Float16* __restrict__ W1t,   // [128][256]
    const _Float16* __restrict__ W2t,   // [128][128]
    const float* __restrict__ b1, const float* __restrict__ b2,
    const float* __restrict__ lng, const float* __restrict__ lnb,
    float* __restrict__ h, _Float16* __restrict__ hh_out) {
    __shared__ __align__(16) _Float16 shA[64 * 264];
    __shared__ __align__(16) _Float16 shM[64 * 136];   // silu(m1), then u+b2 (fp16)
    __shared__ float shB1[HD], shB2[HD], shG[HD], shBt[HD];

    const int tid = threadIdx.x;
    const int w = tid >> 6, l = tid & 63;
    const int lg = l >> 4, lr = l & 15;

    f16x8 w1f[2][8], w2f[2][4];
#pragma unroll
    for (int cf = 0; cf < 2; cf++) {
        const int col = w * 32 + cf * 16 + lr;
#pragma unroll
        for (int s = 0; s < 8; s++)
            w1f[cf][s] = *(const f16x8*)(W1t + (size_t)col * 256 + s * 32 + lg * 8);
#pragma unroll
        for (int s = 0; s < 4; s++)
            w2f[cf][s] = *(const f16x8*)(W2t + (size_t)col * 128 + s * 32 + lg * 8);
    }
    if (tid < 128) { shB1[tid] = b1[tid]; shB2[tid] = b2[tid]; }
    else { shG[tid - 128] = lng[tid - 128]; shBt[tid - 128] = lnb[tid - 128]; }
    __syncthreads();

    int t1 = blockIdx.x * tpb + tpb;
    if (t1 > ntiles) t1 = ntiles;
    for (int t = blockIdx.x * tpb; t < t1; t++) {
        const int n0 = t * 64;

        // stage A: [hh[n] | fp16(agg[n])]; zero agg in place after reading
#pragma unroll
        for (int it = 0; it < 8; it++) {
            int flat = tid + it * 256;
            int e = flat >> 5, c = flat & 31;
            int n = n0 + e;
            f16x8 v = {};
            if (n < N) {
                if (c < 16) {
                    v = *(const f16x8*)(hh_in + (size_t)n * HD + c * 8);
                } else {
                    float* s = agg + (size_t)n * HD + (c - 16) * 8;
                    float4 v0 = *(const float4*)s;
                    float4 v1 = *(const float4*)(s + 4);
                    v[0] = (_Float16)v0.x; v[1] = (_Float16)v0.y;
                    v[2] = (_Float16)v0.z; v[3] = (_Float16)v0.w;
                    v[4] = (_Float16)v1.x; v[5] = (_Float16)v1.y;
                    v[6] = (_Float16)v1.z; v[7] = (_Float16)v1.w;
                    float4 z4 = make_float4(0.f, 0.f, 0.f, 0.f);
                    *(float4*)s = z4;
                    *(float4*)(s + 4) = z4;
                }
            }
            *(f16x8*)&shA[e * 264 + c * 8] = v;
        }
        lds_barrier();                 // B1

        f32x4 acc[4][2];
#pragma unroll
        for (int rf = 0; rf < 4; rf++)
#pragma unroll
            for (int cf = 0; cf < 2; cf++) acc[rf][cf] = (f32x4){0.f, 0.f, 0.f, 0.f};

#pragma unroll
        for (int s = 0; s < 8; s++) {
#pragma unroll
            for (int rf = 0; rf < 4; rf++) {
                f16x8 a = *(const f16x8*)&shA[(rf * 16 + lr) * 264 + s * 32 + lg * 8];
                acc[rf][0] = __builtin_amdgcn_mfma_f32_16x16x32_f16(a, w1f[0][s], acc[rf][0], 0, 0, 0);
                acc[rf][1] = __builtin_amdgcn_mfma_f32_16x16x32_f16(a, w1f[1][s], acc[rf][1], 0, 0, 0);
            }
        }
#pragma unroll
        for (int rf = 0; rf < 4; rf++)
#pragma unroll
            for (int cf = 0; cf < 2; cf++) {
                const int col = w * 32 + cf * 16 + lr;
#pragma unroll
                for (int r = 0; r < 4; r++) {
                    int row = rf * 16 + lg * 4 + r;
                    shM[row * 136 + col] = (_Float16)silu_f(acc[rf][cf][r] + shB1[col]);
                }
            }
        lds_barrier();                 // B3

        f32x4 acc2[4][2];
#pragma unroll
        for (int rf = 0; rf < 4; rf++)
#pragma unroll
            for (int cf = 0; cf < 2; cf++) acc2[rf][cf] = (f32x4){0.f, 0.f, 0.f, 0.f};

#pragma unroll
        for (int s = 0; s < 4; s++) {
#pragma unroll
            for (int rf = 0; rf < 4; rf++) {
                f16x8 a = *(const f16x8*)&shM[(rf * 16 + lr) * 136 + s * 32 + lg * 8];
                acc2[rf][0] = __builtin_amdgcn_mfma_f32_16x16x32_f16(a, w2f[0][s], acc2[rf][0], 0, 0, 0);
                acc2[rf][1] = __builtin_amdgcn_mfma_f32_16x16x32_f16(a, w2f[1][s], acc2[rf][1], 0, 0, 0);
            }
        }
        lds_barrier();                 // B4

        // epilogue: u + b2 -> shM (fp16, reuse)
#pragma unroll
        for (int rf = 0; rf < 4; rf++)
#pragma unroll
            for (int cf = 0; cf < 2; cf++) {
                const int col = w * 32 + cf * 16 + lr;
#pragma unroll
                for (int r = 0; r < 4; r++) {
                    int row = rf * 16 + lg * 4 + r;
                    shM[row * 136 + col] = (_Float16)(acc2[rf][cf][r] + shB2[col]);
                }
            }
        lds_barrier();                 // B5

        // fused residual + LayerNorm: 4 threads per row, 32 cols each
        {
            int row = tid >> 2, q = tid & 3, n = n0 + row;
            float s = 0.f, ss = 0.f;
            if (n < N) {
#pragma unroll
                for (int j = 0; j < 8; j++) {
                    float4 hv = *(const float4*)&h[(size_t)n * HD + q * 32 + j * 4];
                    int cb = q * 32 + j * 4;
                    f16x4 uv = *(const f16x4*)&shM[row * 136 + cb];
                    float x0 = (float)uv[0] + hv.x;
                    float x1 = (float)uv[1] + hv.y;
                    float x2 = (float)uv[2] + hv.z;
                    float x3 = (float)uv[3] + hv.w;
                    s += x0 + x1 + x2 + x3;
                    ss += x0 * x0 + x1 * x1 + x2 * x2 + x3 * x3;
                }
            }
            s += __shfl_xor(s, 1);  s += __shfl_xor(s, 2);
            ss += __shfl_xor(ss, 1); ss += __shfl_xor(ss, 2);
            float mean = s * (1.f / 128.f);
            float var = ss * (1.f / 128.f) - mean * mean;
            float rstd = rsqrtf(var + 1e-5f);
            if (n < N) {
#pragma unroll
                for (int j = 0; j < 8; j++) {
                    float4 hv = *(const float4*)&h[(size_t)n * HD + q * 32 + j * 4];
                    int cb = q * 32 + j * 4;
                    f16x4 uv = *(const f16x4*)&shM[row * 136 + cb];
                    float4 y;
                    y.x = ((float)uv[0] + hv.x - mean) * rstd * shG[cb + 0] + shBt[cb + 0];
                    y.y = ((float)uv[1] + hv.y - mean) * rstd * shG[cb + 1] + shBt[cb + 1];
                    y.z = ((float)uv[2] + hv.z - mean) * rstd * shG[cb + 2] + shBt[cb + 2];
                    y.w = ((float)uv[3] + hv.w - mean) * rstd * shG[cb + 3] + shBt[cb + 3];
                    *(float4*)&h[(size_t)n * HD + cb] = y;
                    f16x4 yh;
                    yh[0] = (_Float16)y.x; yh[1] = (_Float16)y.y;
                    yh[2] = (_Float16)y.z; yh[3] = (_Float16)y.w;
                    *(f16x4*)&hh_out[(size_t)n * HD + cb] = yh;
                }
            }
        }
    }
}

// ---------------- pooling stage 1 ----------------
__global__ __launch_bounds__(256) void k_pool1(const float* __restrict__ h,
                                               float* __restrict__ partial,
                                               int N, int RPB) {
    int bk = blockIdx.x, t = threadIdx.x;
    int j = t & 127, half = t >> 7;
    float s = 0.f;
    int rend = (bk + 1) * RPB; if (rend > N) rend = N;
    for (int r = bk * RPB + half; r < rend; r += 2) s += h[(size_t)r * HD + j];
    __shared__ float sh[256];
    sh[t] = s;
    __syncthreads();
    if (t < 128) partial[bk * HD + j] = sh[t] + sh[t + 128];
}

// ---------------- pooling stage 2 + head MLP ----------------
__global__ __launch_bounds__(128) void k_head(const float* __restrict__ partial,
                                              int nPart, int N,
                                              const float* __restrict__ hw1,
                                              const float* __restrict__ hb1,
                                              const float* __restrict__ hw2,
                                              const float* __restrict__ hb2,
                                              float* __restrict__ out) {
    __shared__ float pooled[HD];
    __shared__ float t1[HD];
    int j = threadIdx.x;
    double s = 0.0;
    for (int bk = 0; bk < nPart; bk++) s += (double)partial[bk * HD + j];
    pooled[j] = (float)(s / (double)N);
    __syncthreads();
    float acc = hb1[j];
    for (int k = 0; k < HD; k++) acc = fmaf(pooled[k], hw1[k * HD + j], acc);
    t1[j] = silu_f(acc) * hw2[j];
    __syncthreads();
    if (j < 64) t1[j] += t1[j + 64];
    __syncthreads();
    if (j < 64) {
        float v = t1[j];
#pragma unroll
        for (int o = 32; o > 0; o >>= 1) v += __shfl_xor(v, o);
        if (j == 0) out[0] = v + hb2[0];
    }
}

extern "C" void kernel_launch(void* const* d_in, const int* in_sizes, int n_in,
                              void* d_out, int out_size, void* d_ws, size_t ws_size,
                              hipStream_t stream) {
    const int* z      = (const int*)d_in[0];
    const float* pos  = (const float*)d_in[1];
    const int* ei     = (const int*)d_in[2];
    const float* lam  = (const float*)d_in[3];
    const float* aemb = (const float*)d_in[4];
    const float* lamw = (const float*)d_in[5];
    const float* lamb = (const float*)d_in[6];
    const float* ew1  = (const float*)d_in[7];
    const float* eb1  = (const float*)d_in[8];
    const float* ew2  = (const float*)d_in[9];
    const float* eb2  = (const float*)d_in[10];
    const float* nw1  = (const float*)d_in[11];
    const float* nb1  = (const float*)d_in[12];
    const float* nw2  = (const float*)d_in[13];
    const float* nb2  = (const float*)d_in[14];
    const float* lng  = (const float*)d_in[15];
    const float* lnb  = (const float*)d_in[16];
    const float* hw1  = (const float*)d_in[17];
    const float* hb1  = (const float*)d_in[18];
    const float* hw2  = (const float*)d_in[19];
    const float* hb2  = (const float*)d_in[20];

    const int N = in_sizes[0];
    const int E = in_sizes[2] / 2;
    const int etiles = (E + 63) / 64;
    const int Epad = etiles * 64;
    const int ntilesN = (N + 63) / 64;

    char* ws = (char*)d_ws;
    size_t off = 0;
    auto alloc = [&](size_t bytes) { void* p = ws + off; off += (bytes + 255) & ~(size_t)255; return p; };
    float* h        = (float*)alloc((size_t)N * HD * 4);
    float* agg      = (float*)alloc((size_t)N * HD * 4);
    _Float16* hh    = (_Float16*)alloc((size_t)N * HD * 2);
    _Float16* Ph    = (_Float16*)alloc((size_t)N * HD * 2);
    _Float16* Qh    = (_Float16*)alloc((size_t)N * HD * 2);
    int* deg        = (int*)alloc((size_t)N * 4);
    int* cursor     = (int*)alloc((size_t)N * 4);
    int* perm       = (int*)alloc((size_t)E * 4);
    int* rowS       = (int*)alloc((size_t)Epad * 4);
    int* colS       = (int*)alloc((size_t)Epad * 4);
    float* distS    = (float*)alloc((size_t)Epad * 4);
    unsigned long long* maskBuf = (unsigned long long*)alloc((size_t)etiles * 8);
    float* lamv     = (float*)alloc(HD * 4);
    float* c1       = (float*)alloc(NLAYER * HD * 4);
    _Float16* c1h   = (_Float16*)alloc(NLAYER * HD * 2);
    float* wd       = (float*)alloc(NLAYER * HD * 4);
    _Float16* wdh   = (_Float16*)alloc(NLAYER * HD * 2);
    float* part     = (float*)alloc(256 * HD * 4);
    _Float16* W1te  = (_Float16*)alloc((size_t)NLAYER * 128 * 256 * 2);
    _Float16* W1tn  = (_Float16*)alloc((size_t)NLAYER * 128 * 256 * 2);
    _Float16* W2te  = (_Float16*)alloc((size_t)NLAYER * 128 * 128 * 2);
    _Float16* W2tn  = (_Float16*)alloc((size_t)NLAYER * 128 * 128 * 2);

    // --- setup (once per launch) ---
    k_init<<<NLAYER, 128, 0, stream>>>(lam, lamw, lamb, ew1, eb1, lamv, c1, c1h);
    int prepTot = NLAYER * 128 * 256 * 2 + NLAYER * 128 * 128 * 2 + NLAYER * 128;
    k_prep<<<(prepTot + 255) / 256, 256, 0, stream>>>(ew1, ew2, nw1, nw2,
                                                      W1te, W2te, W1tn, W2tn, wd, wdh);
    int n4 = N * 32;
    k_embed<<<(n4 + 255) / 256, 256, 0, stream>>>(z, aemb, lamv, h, hh, n4);

    // --- counting sort of edges by row + boundary masks ---
    k_zero<<<64, 256, 0, stream>>>((float4*)deg, (N + 3) / 4);
    k_hist<<<(E + 255) / 256, 256, 0, stream>>>(ei, deg, E);
    k_scan<<<1, 1024, 0, stream>>>(deg, cursor, N);
    k_scatter<<<(E + 255) / 256, 256, 0, stream>>>(ei, cursor, perm, E);
    k_apply<<<(Epad + 255) / 256, 256, 0, stream>>>(perm, ei, pos, rowS, colS, distS, E, Epad);
    k_mask<<<(Epad + 255) / 256, 256, 0, stream>>>(rowS, maskBuf, Epad);

    // agg zero once (layer 0); k_node re-zeroes in place for subsequent layers
    int zero4 = N * (HD / 4);
    k_zero<<<2048, 256, 0, stream>>>((float4*)agg, zero4);

    // --- layer loop ---
    const int egrid = (etiles < 768) ? etiles : 768;   // 3 blocks/CU at (512,6)
    const int etpb = (etiles + egrid - 1) / egrid;
    const int ngrid = (ntilesN + 1) / 2;               // tpb=2
    for (int l = 0; l < NLAYER; l++) {
        k_pq<<<ntilesN, 512, 0, stream>>>(hh, N, W1te + (size_t)l * 128 * 256, Ph, Qh);
        k_edge_mfma<<<egrid, 512, 0, stream>>>(Ph, Qh, rowS, colS, distS, maskBuf,
            Epad, etiles, etpb,
            W2te + (size_t)l * 128 * 128, wdh + l * HD, c1h + l * HD,
            eb2 + l * HD, agg);
        k_node_mfma<<<ngrid, 256, 0, stream>>>(hh, agg, N, ntilesN, 2,
            W1tn + (size_t)l * 128 * 256, W2tn + (size_t)l * 128 * 128,
            nb1 + l * HD, nb2 + l * HD, lng + l * HD, lnb + l * HD, h, hh);
    }
    int RPB = (N + 255) / 256;
    k_pool1<<<256, 256, 0, stream>>>(h, part, N, RPB);
    k_head<<<1, 128, 0, stream>>>(part, 256, N, hw1, hb1, hw2, hb2, (float*)d_out);
}

// Round 17
// 879.890 us; speedup vs baseline: 1.0275x; 1.0275x over previous
//
#include <hip/hip_runtime.h>
#include <cstdint>
#include <cstddef>

#define HD 128
#define NLAYER 4
#define EINDIM 385

typedef _Float16 f16x8 __attribute__((ext_vector_type(8)));
typedef _Float16 f16x4 __attribute__((ext_vector_type(4)));
typedef float f32x4 __attribute__((ext_vector_type(4)));

// fast silu: v_mul+v_exp+v_add+v_rcp+v_mul (no IEEE divide)
__device__ __forceinline__ float silu_f(float x) {
    float e = __expf(-x);
    return x * __builtin_amdgcn_rcpf(1.f + e);
}

// LDS-only barrier: does NOT drain vmcnt -> prefetch loads stay in flight
__device__ __forceinline__ void lds_barrier() {
    asm volatile("s_waitcnt lgkmcnt(0)" ::: "memory");
    __builtin_amdgcn_s_barrier();
}

// ---------------- init: lam_vec + folded edge bias c1 (fp32 + fp16) ----------------
__global__ __launch_bounds__(128) void k_init(const float* __restrict__ lam_p,
                                              const float* __restrict__ lam_w,
                                              const float* __restrict__ lam_b,
                                              const float* __restrict__ edge_w1,
                                              const float* __restrict__ edge_b1,
                                              float* __restrict__ lam_vec,
                                              float* __restrict__ c1,
                                              _Float16* __restrict__ c1h) {
    __shared__ float sl[HD];
    const int j = threadIdx.x;   // 0..127
    const int l = blockIdx.x;    // 0..NLAYER-1
    float lam = lam_p[0];
    float v = lam * lam_w[j] + lam_b[j];
    sl[j] = v;
    if (l == 0) lam_vec[j] = v;
    __syncthreads();
    float acc = edge_b1[l * HD + j];
    const float* w = edge_w1 + ((size_t)l * EINDIM + 257) * HD + j;
#pragma unroll 8
    for (int k = 0; k < HD; k++) acc = fmaf(sl[k], w[(size_t)k * HD], acc);
    c1[l * HD + j] = acc;
    c1h[l * HD + j] = (_Float16)acc;
}

// ---------------- prep: transpose weights to [col][k] fp16, extract dist row ----------------
__global__ void k_prep(const float* __restrict__ ew1, const float* __restrict__ ew2,
                       const float* __restrict__ nw1, const float* __restrict__ nw2,
                       _Float16* __restrict__ W1te, _Float16* __restrict__ W2te,
                       _Float16* __restrict__ W1tn, _Float16* __restrict__ W2tn,
                       float* __restrict__ wd, _Float16* __restrict__ wdh) {
    int t = blockIdx.x * 256 + threadIdx.x;
    if (t < NLAYER * 128 * 256) {
        int l = t >> 15, r = t & 32767, j = r >> 8, k = r & 255;
        W1te[t] = (_Float16)ew1[((size_t)l * EINDIM + k) * HD + j];
        return;
    }
    t -= NLAYER * 128 * 256;
    if (t < NLAYER * 128 * 256) {
        int l = t >> 15, r = t & 32767, j = r >> 8, k = r & 255;
        W1tn[t] = (_Float16)nw1[((size_t)l * 256 + k) * HD + j];
        return;
    }
    t -= NLAYER * 128 * 256;
    if (t < NLAYER * 128 * 128) {
        int l = t >> 14, r = t & 16383, j = r >> 7, k = r & 127;
        W2te[t] = (_Float16)ew2[((size_t)l * 128 + k) * HD + j];
        return;
    }
    t -= NLAYER * 128 * 128;
    if (t < NLAYER * 128 * 128) {
        int l = t >> 14, r = t & 16383, j = r >> 7, k = r & 127;
        W2tn[t] = (_Float16)nw2[((size_t)l * 128 + k) * HD + j];
        return;
    }
    t -= NLAYER * 128 * 128;
    if (t < NLAYER * 128) {
        int l = t >> 7, j = t & 127;
        float v = ew1[((size_t)l * EINDIM + 256) * HD + j];
        wd[t] = v;
        wdh[t] = (_Float16)v;
    }
}

// ---------------- h0 = atom_embed[z] + lam_vec (fp32 + fp16 copies) ----------------
__global__ void k_embed(const int* __restrict__ z,
                        const float* __restrict__ atom_embed,
                        const float* __restrict__ lam_vec,
                        float* __restrict__ h, _Float16* __restrict__ hh, int n4) {
    int i = blockIdx.x * 256 + threadIdx.x;
    if (i >= n4) return;
    int n = i >> 5, q = i & 31;
    int a = z[n];
    float4 e = *(const float4*)&atom_embed[(size_t)a * HD + q * 4];
    float4 lv = *(const float4*)&lam_vec[q * 4];
    e.x += lv.x; e.y += lv.y; e.z += lv.z; e.w += lv.w;
    *(float4*)&h[(size_t)n * HD + q * 4] = e;
    f16x4 hv;
    hv[0] = (_Float16)e.x; hv[1] = (_Float16)e.y;
    hv[2] = (_Float16)e.z; hv[3] = (_Float16)e.w;
    *(f16x4*)&hh[(size_t)n * HD + q * 4] = hv;
}

// ---------------- generic zero ----------------
__global__ void k_zero(float4* __restrict__ p, int n4) {
    for (int i = blockIdx.x * 256 + threadIdx.x; i < n4; i += gridDim.x * 256)
        p[i] = make_float4(0.f, 0.f, 0.f, 0.f);
}

// ---------------- counting sort: histogram ----------------
__global__ void k_hist(const int* __restrict__ ei, int* __restrict__ deg, int E) {
    int e = blockIdx.x * 256 + threadIdx.x;
    if (e < E) atomicAdd(&deg[ei[e]], 1);
}

// ---------------- counting sort: single-block scan deg -> cursor ----------------
__global__ __launch_bounds__(1024) void k_scan(const int* __restrict__ deg,
                                               int* __restrict__ cursor, int N) {
    __shared__ int part[1024];
    int t = threadIdx.x;
    int chunk = (N + 1023) >> 10;
    int s0 = t * chunk, s1 = s0 + chunk;
    if (s1 > N) s1 = N;
    int s = 0;
    for (int i = s0; i < s1; i++) s += deg[i];
    part[t] = s;
    __syncthreads();
    for (int d = 1; d < 1024; d <<= 1) {
        int v = (t >= d) ? part[t - d] : 0;
        __syncthreads();
        part[t] += v;
        __syncthreads();
    }
    int base = (t == 0) ? 0 : part[t - 1];
    for (int i = s0; i < s1; i++) {
        cursor[i] = base;
        base += deg[i];
    }
}

// ---------------- counting sort: scatter permutation ----------------
__global__ void k_scatter(const int* __restrict__ ei, int* __restrict__ cursor,
                          int* __restrict__ perm, int E) {
    int e = blockIdx.x * 256 + threadIdx.x;
    if (e < E) {
        int p = atomicAdd(&cursor[ei[e]], 1);
        perm[p] = e;
    }
}

// ---------------- apply perm: rowS/colS/distS (sorted by row) ----------------
__global__ void k_apply(const int* __restrict__ perm, const int* __restrict__ ei,
                        const float* __restrict__ pos,
                        int* __restrict__ rowS, int* __restrict__ colS,
                        float* __restrict__ distS, int E, int Epad) {
    int i = blockIdx.x * 256 + threadIdx.x;
    if (i >= Epad) return;
    if (i < E) {
        int e = perm[i];
        int r = ei[e], c = ei[E + e];
        rowS[i] = r; colS[i] = c;
        float dx = pos[r * 3 + 0] - pos[c * 3 + 0];
        float dy = pos[r * 3 + 1] - pos[c * 3 + 1];
        float dz = pos[r * 3 + 2] - pos[c * 3 + 2];
        distS[i] = sqrtf(dx * dx + dy * dy + dz * dz + 1e-8f);
    } else {
        rowS[i] = -1; colS[i] = 0; distS[i] = 0.f;
    }
}

// ---------------- per-tile boundary masks: bit i = rowS[i] != rowS[i+1] ----------------
__global__ void k_mask(const int* __restrict__ rowS,
                       unsigned long long* __restrict__ maskBuf, int Epad) {
    int i = blockIdx.x * 256 + threadIdx.x;
    if (i >= Epad) return;   // Epad multiple of 64: whole waves uniform
    bool pred = (i + 1 >= Epad) ? true : (rowS[i] != rowS[i + 1]);
    unsigned long long m = __ballot(pred);
    if ((i & 63) == 0) maskBuf[i >> 6] = m;
}

// =======================================================================
// per-node edge-message precompute: P = h @ W1a, Q = h @ W1b (fp16 out).
// 512 threads / 8 waves x 16 cols; dense 64-row tiles; K=128 each.
// =======================================================================
__global__ __launch_bounds__(512, 4) void k_pq(
    const _Float16* __restrict__ hh, int N,
    const _Float16* __restrict__ W1t,   // [128][256] (k<128: h_row part, k>=128: h_col part)
    _Float16* __restrict__ Ph, _Float16* __restrict__ Qh) {
    __shared__ __align__(16) _Float16 shH[64 * 136];
    const int tid = threadIdx.x;
    const int w = tid >> 6, l = tid & 63;
    const int lg = l >> 4, lr = l & 15;
    const int col = w * 16 + lr;

    f16x8 w1a[4], w1b[4];
#pragma unroll
    for (int s = 0; s < 4; s++) {
        w1a[s] = *(const f16x8*)(W1t + (size_t)col * 256 + s * 32 + lg * 8);
        w1b[s] = *(const f16x8*)(W1t + (size_t)col * 256 + 128 + s * 32 + lg * 8);
    }
    const int n0 = blockIdx.x * 64;
#pragma unroll
    for (int it = 0; it < 2; it++) {
        int flat = tid + it * 512;
        int e = flat >> 4, c = flat & 15;
        int n = n0 + e;
        f16x8 v = {};
        if (n < N) v = *(const f16x8*)(hh + (size_t)n * HD + c * 8);
        *(f16x8*)&shH[e * 136 + c * 8] = v;
    }
    __syncthreads();

    f32x4 aP[4], aQ[4];
#pragma unroll
    for (int rf = 0; rf < 4; rf++) { aP[rf] = (f32x4){0,0,0,0}; aQ[rf] = (f32x4){0,0,0,0}; }
#pragma unroll
    for (int s = 0; s < 4; s++) {
#pragma unroll
        for (int rf = 0; rf < 4; rf++) {
            f16x8 a = *(const f16x8*)&shH[(rf * 16 + lr) * 136 + s * 32 + lg * 8];
            aP[rf] = __builtin_amdgcn_mfma_f32_16x16x32_f16(a, w1a[s], aP[rf], 0, 0, 0);
            aQ[rf] = __builtin_amdgcn_mfma_f32_16x16x32_f16(a, w1b[s], aQ[rf], 0, 0, 0);
        }
    }
#pragma unroll
    for (int rf = 0; rf < 4; rf++) {
#pragma unroll
        for (int r = 0; r < 4; r++) {
            int n = n0 + rf * 16 + lg * 4 + r;
            if (n < N) {
                Ph[(size_t)n * HD + col] = (_Float16)aP[rf][r];
                Qh[(size_t)n * HD + col] = (_Float16)aQ[rf][r];
            }
        }
    }
}

// =======================================================================
// edge kernel v2: NO edge GEMM1.  m1 = silu(P[row]+Q[col]+dist*wd+c1)
// computed during staging (packed-fp16 add chain, fp32 silu); then
// GEMM2 (W2 in 16 regs/thread), ep2, mask-driven segmented reduce.
// (512,4): PROVEN no-spill point; (512,6) spilled the pipeline regs
// (round 16: FETCH 70->102MB, dur +8us).
// =======================================================================
__global__ __launch_bounds__(512, 4) void k_edge_mfma(
    const _Float16* __restrict__ Ph, const _Float16* __restrict__ Qh,
    const int* __restrict__ rowS, const int* __restrict__ colS,
    const float* __restrict__ distS,
    const unsigned long long* __restrict__ maskBuf,
    int Epad, int ntiles, int tpb,
    const _Float16* __restrict__ W2t,   // [128][128] fp16
    const _Float16* __restrict__ wdh, const _Float16* __restrict__ c1h,
    const float* __restrict__ b2,
    float* __restrict__ agg) {
    __shared__ __align__(16) _Float16 shM[64 * 136];   // m1, then final m2 (fp16)
    __shared__ int shRow2[2][64];

    const int tid = threadIdx.x;
    const int w = tid >> 6, l = tid & 63;
    const int lg = l >> 4, lr = l & 15;
    const int col = w * 16 + lr;
    const int cc = tid & 15;              // staging chunk (cols cc*8..cc*8+7)

    f16x8 w2f[4];
#pragma unroll
    for (int s = 0; s < 4; s++)
        w2f[s] = *(const f16x8*)(W2t + (size_t)col * 128 + s * 32 + lg * 8);
    const f16x8 wd8 = *(const f16x8*)(wdh + cc * 8);
    const f16x8 c18 = *(const f16x8*)(c1h + cc * 8);
    const float b2v = b2[col];

    const int t0 = blockIdx.x * tpb;
    int t1 = t0 + tpb; if (t1 > ntiles) t1 = ntiles;
    if (t0 >= t1) return;   // uniform per block

    // prefetch pipeline registers
    f16x8 vP[2], vQ[2];
    float dva[2];
    int rv = -1;

    // ---- prologue: gather tile t0 ----
    {
        const int e0 = t0 * 64;
        if (tid < 64) rv = rowS[e0 + tid];
#pragma unroll
        for (int it = 0; it < 2; it++) {
            int e = (tid + it * 512) >> 4;
            int r_ = rowS[e0 + e], q_ = colS[e0 + e];
            if (r_ < 0) r_ = 0;
            vP[it] = *(const f16x8*)(Ph + (size_t)r_ * HD + cc * 8);
            vQ[it] = *(const f16x8*)(Qh + (size_t)q_ * HD + cc * 8);
            dva[it] = distS[e0 + e];
        }
    }

    for (int t = t0; t < t1; t++) {
        const int pb = t & 1;
        const unsigned long long bmCur = maskBuf[t];
        const unsigned long long bmPrev = (t > 0) ? maskBuf[t - 1] : ~0ull;

        lds_barrier();                 // B0: prev tile's segreduce reads done

        // stage: m1 = silu(P[row]+Q[col]+dist*wd+c1) -> shM
        // add-chain in packed fp16 (v_pk_add/pk_fma); silu in fp32
#pragma unroll
        for (int it = 0; it < 2; it++) {
            int e = (tid + it * 512) >> 4;
            _Float16 dh = (_Float16)dva[it];
            f16x8 x = vP[it] + vQ[it] + dh * wd8 + c18;
            f16x8 mv;
#pragma unroll
            for (int j = 0; j < 8; j++)
                mv[j] = (_Float16)silu_f((float)x[j]);
            *(f16x8*)&shM[e * 136 + cc * 8] = mv;
        }
        if (tid < 64) shRow2[pb][tid] = rv;

        // prefetch tile t+1 (loads fly across the lds-only barriers)
        {
            int tn = t + 1; if (tn > ntiles - 1) tn = ntiles - 1;
            const int e0n = tn * 64;
#pragma unroll
            for (int it = 0; it < 2; it++) {
                int e = (tid + it * 512) >> 4;
                int r_ = rowS[e0n + e], q_ = colS[e0n + e];
                if (r_ < 0) r_ = 0;
                vP[it] = *(const f16x8*)(Ph + (size_t)r_ * HD + cc * 8);
                vQ[it] = *(const f16x8*)(Qh + (size_t)q_ * HD + cc * 8);
                dva[it] = distS[e0n + e];
            }
            if (tid < 64) rv = rowS[e0n + tid];
        }

        lds_barrier();                 // B1: shM(t) + shRow visible

        f32x4 acc[4];
#pragma unroll
        for (int rf = 0; rf < 4; rf++) acc[rf] = (f32x4){0.f, 0.f, 0.f, 0.f};

        // GEMM2: K=128, barrier-free (B in registers)
#pragma unroll
        for (int s = 0; s < 4; s++) {
#pragma unroll
            for (int rf = 0; rf < 4; rf++) {
                f16x8 a = *(const f16x8*)&shM[(rf * 16 + lr) * 136 + s * 32 + lg * 8];
                acc[rf] = __builtin_amdgcn_mfma_f32_16x16x32_f16(a, w2f[s], acc[rf], 0, 0, 0);
            }
        }
        lds_barrier();                 // B4: all GEMM2 reads done before overwrite

        // ep2: silu -> shM (fp16, reuse)
#pragma unroll
        for (int rf = 0; rf < 4; rf++) {
#pragma unroll
            for (int r = 0; r < 4; r++) {
                int row = rf * 16 + lg * 4 + r;
                shM[row * 136 + col] = (_Float16)silu_f(acc[rf][r] + b2v);
            }
        }
        lds_barrier();                 // B5: final m visible

        // mask-driven segmented reduction: 4 quarter-tiles x 128 cols
        {
            const int scol = tid & 127, quarter = tid >> 7;   // 0..3
            const int i0 = quarter << 4;                      // 16 rows each
            const unsigned int mh = (unsigned int)(bmCur >> i0) & 0xFFFFu;
            bool open = (quarter == 0) ? !((bmPrev >> 63) & 1ull)
                                       : !((bmCur >> (i0 - 1)) & 1ull);
            float s = 0.f;
#pragma unroll
            for (int ib = 0; ib < 4; ib++) {
                const int i = i0 + ib * 4;
                float v0 = (float)shM[(i + 0) * 136 + scol];
                float v1 = (float)shM[(i + 1) * 136 + scol];
                float v2 = (float)shM[(i + 2) * 136 + scol];
                float v3 = (float)shM[(i + 3) * 136 + scol];
#pragma unroll
                for (int q = 0; q < 4; q++) {
                    s += (q == 0) ? v0 : (q == 1) ? v1 : (q == 2) ? v2 : v3;
                    if (mh & (1u << (ib * 4 + q))) {
                        int rc = shRow2[pb][i + q];
                        if (rc >= 0) {
                            if (open) atomicAdd(&agg[(size_t)rc * HD + scol], s);
                            else      agg[(size_t)rc * HD + scol] = s;
                        }
                        s = 0.f;
                        open = false;
                    }
                }
            }
            if (!((mh >> 15) & 1u)) {
                int rc = shRow2[pb][i0 + 15];
                if (rc >= 0) atomicAdd(&agg[(size_t)rc * HD + scol], s);
            }
        }
    }
}

// =======================================================================
// node MLP via MFMA fp16 + fused residual + LayerNorm.  (256,3).
// Staging also ZEROES agg in place (exclusive per tile).  [unchanged]
// =======================================================================
__global__ __launch_bounds__(256, 3) void k_node_mfma(
    const _Float16* __restrict__ hh_in, float* __restrict__ agg, int N,
    int ntiles, int tpb,
    const _Float16* __restrict__ W1t,   // [128][256]
    const _Float16* __restrict__ W2t,   // [128][128]
    const float* __restrict__ b1, const float* __restrict__ b2,
    const float* __restrict__ lng, const float* __restrict__ lnb,
    float* __restrict__ h, _Float16* __restrict__ hh_out) {
    __shared__ __align__(16) _Float16 shA[64 * 264];
    __shared__ __align__(16) _Float16 shM[64 * 136];   // silu(m1), then u+b2 (fp16)
    __shared__ float shB1[HD], shB2[HD], shG[HD], shBt[HD];

    const int tid = threadIdx.x;
    const int w = tid >> 6, l = tid & 63;
    const int lg = l >> 4, lr = l & 15;

    f16x8 w1f[2][8], w2f[2][4];
#pragma unroll
    for (int cf = 0; cf < 2; cf++) {
        const int col = w * 32 + cf * 16 + lr;
#pragma unroll
        for (int s = 0; s < 8; s++)
            w1f[cf][s] = *(const f16x8*)(W1t + (size_t)col * 256 + s * 32 + lg * 8);
#pragma unroll
        for (int s = 0; s < 4; s++)
            w2f[cf][s] = *(const f16x8*)(W2t + (size_t)col * 128 + s * 32 + lg * 8);
    }
    if (tid < 128) { shB1[tid] = b1[tid]; shB2[tid] = b2[tid]; }
    else { shG[tid - 128] = lng[tid - 128]; shBt[tid - 128] = lnb[tid - 128]; }
    __syncthreads();

    int t1 = blockIdx.x * tpb + tpb;
    if (t1 > ntiles) t1 = ntiles;
    for (int t = blockIdx.x * tpb; t < t1; t++) {
        const int n0 = t * 64;

        // stage A: [hh[n] | fp16(agg[n])]; zero agg in place after reading
#pragma unroll
        for (int it = 0; it < 8; it++) {
            int flat = tid + it * 256;
            int e = flat >> 5, c = flat & 31;
            int n = n0 + e;
            f16x8 v = {};
            if (n < N) {
                if (c < 16) {
                    v = *(const f16x8*)(hh_in + (size_t)n * HD + c * 8);
                } else {
                    float* s = agg + (size_t)n * HD + (c - 16) * 8;
                    float4 v0 = *(const float4*)s;
                    float4 v1 = *(const float4*)(s + 4);
                    v[0] = (_Float16)v0.x; v[1] = (_Float16)v0.y;
                    v[2] = (_Float16)v0.z; v[3] = (_Float16)v0.w;
                    v[4] = (_Float16)v1.x; v[5] = (_Float16)v1.y;
                    v[6] = (_Float16)v1.z; v[7] = (_Float16)v1.w;
                    float4 z4 = make_float4(0.f, 0.f, 0.f, 0.f);
                    *(float4*)s = z4;
                    *(float4*)(s + 4) = z4;
                }
            }
            *(f16x8*)&shA[e * 264 + c * 8] = v;
        }
        lds_barrier();                 // B1

        f32x4 acc[4][2];
#pragma unroll
        for (int rf = 0; rf < 4; rf++)
#pragma unroll
            for (int cf = 0; cf < 2; cf++) acc[rf][cf] = (f32x4){0.f, 0.f, 0.f, 0.f};

#pragma unroll
        for (int s = 0; s < 8; s++) {
#pragma unroll
            for (int rf = 0; rf < 4; rf++) {
                f16x8 a = *(const f16x8*)&shA[(rf * 16 + lr) * 264 + s * 32 + lg * 8];
                acc[rf][0] = __builtin_amdgcn_mfma_f32_16x16x32_f16(a, w1f[0][s], acc[rf][0], 0, 0, 0);
                acc[rf][1] = __builtin_amdgcn_mfma_f32_16x16x32_f16(a, w1f[1][s], acc[rf][1], 0, 0, 0);
            }
        }
#pragma unroll
        for (int rf = 0; rf < 4; rf++)
#pragma unroll
            for (int cf = 0; cf < 2; cf++) {
                const int col = w * 32 + cf * 16 + lr;
#pragma unroll
                for (int r = 0; r < 4; r++) {
                    int row = rf * 16 + lg * 4 + r;
                    shM[row * 136 + col] = (_Float16)silu_f(acc[rf][cf][r] + shB1[col]);
                }
            }
        lds_barrier();                 // B3

        f32x4 acc2[4][2];
#pragma unroll
        for (int rf = 0; rf < 4; rf++)
#pragma unroll
            for (int cf = 0; cf < 2; cf++) acc2[rf][cf] = (f32x4){0.f, 0.f, 0.f, 0.f};

#pragma unroll
        for (int s = 0; s < 4; s++) {
#pragma unroll
            for (int rf = 0; rf < 4; rf++) {
                f16x8 a = *(const f16x8*)&shM[(rf * 16 + lr) * 136 + s * 32 + lg * 8];
                acc2[rf][0] = __builtin_amdgcn_mfma_f32_16x16x32_f16(a, w2f[0][s], acc2[rf][0], 0, 0, 0);
                acc2[rf][1] = __builtin_amdgcn_mfma_f32_16x16x32_f16(a, w2f[1][s], acc2[rf][1], 0, 0, 0);
            }
        }
        lds_barrier();                 // B4

        // epilogue: u + b2 -> shM (fp16, reuse)
#pragma unroll
        for (int rf = 0; rf < 4; rf++)
#pragma unroll
            for (int cf = 0; cf < 2; cf++) {
                const int col = w * 32 + cf * 16 + lr;
#pragma unroll
                for (int r = 0; r < 4; r++) {
                    int row = rf * 16 + lg * 4 + r;
                    shM[row * 136 + col] = (_Float16)(acc2[rf][cf][r] + shB2[col]);
                }
            }
        lds_barrier();                 // B5

        // fused residual + LayerNorm: 4 threads per row, 32 cols each
        {
            int row = tid >> 2, q = tid & 3, n = n0 + row;
            float s = 0.f, ss = 0.f;
            if (n < N) {
#pragma unroll
                for (int j = 0; j < 8; j++) {
                    float4 hv = *(const float4*)&h[(size_t)n * HD + q * 32 + j * 4];
                    int cb = q * 32 + j * 4;
                    f16x4 uv = *(const f16x4*)&shM[row * 136 + cb];
                    float x0 = (float)uv[0] + hv.x;
                    float x1 = (float)uv[1] + hv.y;
                    float x2 = (float)uv[2] + hv.z;
                    float x3 = (float)uv[3] + hv.w;
                    s += x0 + x1 + x2 + x3;
                    ss += x0 * x0 + x1 * x1 + x2 * x2 + x3 * x3;
                }
            }
            s += __shfl_xor(s, 1);  s += __shfl_xor(s, 2);
            ss += __shfl_xor(ss, 1); ss += __shfl_xor(ss, 2);
            float mean = s * (1.f / 128.f);
            float var = ss * (1.f / 128.f) - mean * mean;
            float rstd = rsqrtf(var + 1e-5f);
            if (n < N) {
#pragma unroll
                for (int j = 0; j < 8; j++) {
                    float4 hv = *(const float4*)&h[(size_t)n * HD + q * 32 + j * 4];
                    int cb = q * 32 + j * 4;
                    f16x4 uv = *(const f16x4*)&shM[row * 136 + cb];
                    float4 y;
                    y.x = ((float)uv[0] + hv.x - mean) * rstd * shG[cb + 0] + shBt[cb + 0];
                    y.y = ((float)uv[1] + hv.y - mean) * rstd * shG[cb + 1] + shBt[cb + 1];
                    y.z = ((float)uv[2] + hv.z - mean) * rstd * shG[cb + 2] + shBt[cb + 2];
                    y.w = ((float)uv[3] + hv.w - mean) * rstd * shG[cb + 3] + shBt[cb + 3];
                    *(float4*)&h[(size_t)n * HD + cb] = y;
                    f16x4 yh;
                    yh[0] = (_Float16)y.x; yh[1] = (_Float16)y.y;
                    yh[2] = (_Float16)y.z; yh[3] = (_Float16)y.w;
                    *(f16x4*)&hh_out[(size_t)n * HD + cb] = yh;
                }
            }
        }
    }
}

// ---------------- pooling stage 1 ----------------
__global__ __launch_bounds__(256) void k_pool1(const float* __restrict__ h,
                                               float* __restrict__ partial,
                                               int N, int RPB) {
    int bk = blockIdx.x, t = threadIdx.x;
    int j = t & 127, half = t >> 7;
    float s = 0.f;
    int rend = (bk + 1) * RPB; if (rend > N) rend = N;
    for (int r = bk * RPB + half; r < rend; r += 2) s += h[(size_t)r * HD + j];
    __shared__ float sh[256];
    sh[t] = s;
    __syncthreads();
    if (t < 128) partial[bk * HD + j] = sh[t] + sh[t + 128];
}

// ---------------- pooling stage 2 + head MLP ----------------
__global__ __launch_bounds__(128) void k_head(const float* __restrict__ partial,
                                              int nPart, int N,
                                              const float* __restrict__ hw1,
                                              const float* __restrict__ hb1,
                                              const float* __restrict__ hw2,
                                              const float* __restrict__ hb2,
                                              float* __restrict__ out) {
    __shared__ float pooled[HD];
    __shared__ float t1[HD];
    int j = threadIdx.x;
    double s = 0.0;
    for (int bk = 0; bk < nPart; bk++) s += (double)partial[bk * HD + j];
    pooled[j] = (float)(s / (double)N);
    __syncthreads();
    float acc = hb1[j];
    for (int k = 0; k < HD; k++) acc = fmaf(pooled[k], hw1[k * HD + j], acc);
    t1[j] = silu_f(acc) * hw2[j];
    __syncthreads();
    if (j < 64) t1[j] += t1[j + 64];
    __syncthreads();
    if (j < 64) {
        float v = t1[j];
#pragma unroll
        for (int o = 32; o > 0; o >>= 1) v += __shfl_xor(v, o);
        if (j == 0) out[0] = v + hb2[0];
    }
}

extern "C" void kernel_launch(void* const* d_in, const int* in_sizes, int n_in,
                              void* d_out, int out_size, void* d_ws, size_t ws_size,
                              hipStream_t stream) {
    const int* z      = (const int*)d_in[0];
    const float* pos  = (const float*)d_in[1];
    const int* ei     = (const int*)d_in[2];
    const float* lam  = (const float*)d_in[3];
    const float* aemb = (const float*)d_in[4];
    const float* lamw = (const float*)d_in[5];
    const float* lamb = (const float*)d_in[6];
    const float* ew1  = (const float*)d_in[7];
    const float* eb1  = (const float*)d_in[8];
    const float* ew2  = (const float*)d_in[9];
    const float* eb2  = (const float*)d_in[10];
    const float* nw1  = (const float*)d_in[11];
    const float* nb1  = (const float*)d_in[12];
    const float* nw2  = (const float*)d_in[13];
    const float* nb2  = (const float*)d_in[14];
    const float* lng  = (const float*)d_in[15];
    const float* lnb  = (const float*)d_in[16];
    const float* hw1  = (const float*)d_in[17];
    const float* hb1  = (const float*)d_in[18];
    const float* hw2  = (const float*)d_in[19];
    const float* hb2  = (const float*)d_in[20];

    const int N = in_sizes[0];
    const int E = in_sizes[2] / 2;
    const int etiles = (E + 63) / 64;
    const int Epad = etiles * 64;
    const int ntilesN = (N + 63) / 64;

    char* ws = (char*)d_ws;
    size_t off = 0;
    auto alloc = [&](size_t bytes) { void* p = ws + off; off += (bytes + 255) & ~(size_t)255; return p; };
    float* h        = (float*)alloc((size_t)N * HD * 4);
    float* agg      = (float*)alloc((size_t)N * HD * 4);
    _Float16* hh    = (_Float16*)alloc((size_t)N * HD * 2);
    _Float16* Ph    = (_Float16*)alloc((size_t)N * HD * 2);
    _Float16* Qh    = (_Float16*)alloc((size_t)N * HD * 2);
    int* deg        = (int*)alloc((size_t)N * 4);
    int* cursor     = (int*)alloc((size_t)N * 4);
    int* perm       = (int*)alloc((size_t)E * 4);
    int* rowS       = (int*)alloc((size_t)Epad * 4);
    int* colS       = (int*)alloc((size_t)Epad * 4);
    float* distS    = (float*)alloc((size_t)Epad * 4);
    unsigned long long* maskBuf = (unsigned long long*)alloc((size_t)etiles * 8);
    float* lamv     = (float*)alloc(HD * 4);
    float* c1       = (float*)alloc(NLAYER * HD * 4);
    _Float16* c1h   = (_Float16*)alloc(NLAYER * HD * 2);
    float* wd       = (float*)alloc(NLAYER * HD * 4);
    _Float16* wdh   = (_Float16*)alloc(NLAYER * HD * 2);
    float* part     = (float*)alloc(256 * HD * 4);
    _Float16* W1te  = (_Float16*)alloc((size_t)NLAYER * 128 * 256 * 2);
    _Float16* W1tn  = (_Float16*)alloc((size_t)NLAYER * 128 * 256 * 2);
    _Float16* W2te  = (_Float16*)alloc((size_t)NLAYER * 128 * 128 * 2);
    _Float16* W2tn  = (_Float16*)alloc((size_t)NLAYER * 128 * 128 * 2);

    // --- setup (once per launch) ---
    k_init<<<NLAYER, 128, 0, stream>>>(lam, lamw, lamb, ew1, eb1, lamv, c1, c1h);
    int prepTot = NLAYER * 128 * 256 * 2 + NLAYER * 128 * 128 * 2 + NLAYER * 128;
    k_prep<<<(prepTot + 255) / 256, 256, 0, stream>>>(ew1, ew2, nw1, nw2,
                                                      W1te, W2te, W1tn, W2tn, wd, wdh);
    int n4 = N * 32;
    k_embed<<<(n4 + 255) / 256, 256, 0, stream>>>(z, aemb, lamv, h, hh, n4);

    // --- counting sort of edges by row + boundary masks ---
    k_zero<<<64, 256, 0, stream>>>((float4*)deg, (N + 3) / 4);
    k_hist<<<(E + 255) / 256, 256, 0, stream>>>(ei, deg, E);
    k_scan<<<1, 1024, 0, stream>>>(deg, cursor, N);
    k_scatter<<<(E + 255) / 256, 256, 0, stream>>>(ei, cursor, perm, E);
    k_apply<<<(Epad + 255) / 256, 256, 0, stream>>>(perm, ei, pos, rowS, colS, distS, E, Epad);
    k_mask<<<(Epad + 255) / 256, 256, 0, stream>>>(rowS, maskBuf, Epad);

    // agg zero once (layer 0); k_node re-zeroes in place for subsequent layers
    int zero4 = N * (HD / 4);
    k_zero<<<2048, 256, 0, stream>>>((float4*)agg, zero4);

    // --- layer loop ---
    const int egrid = (etiles < 512) ? etiles : 512;   // 2 blocks/CU at (512,4), proven
    const int etpb = (etiles + egrid - 1) / egrid;
    const int ngrid = (ntilesN + 1) / 2;               // tpb=2
    for (int l = 0; l < NLAYER; l++) {
        k_pq<<<ntilesN, 512, 0, stream>>>(hh, N, W1te + (size_t)l * 128 * 256, Ph, Qh);
        k_edge_mfma<<<egrid, 512, 0, stream>>>(Ph, Qh, rowS, colS, distS, maskBuf,
            Epad, etiles, etpb,
            W2te + (size_t)l * 128 * 128, wdh + l * HD, c1h + l * HD,
            eb2 + l * HD, agg);
        k_node_mfma<<<ngrid, 256, 0, stream>>>(hh, agg, N, ntilesN, 2,
            W1tn + (size_t)l * 128 * 256, W2tn + (size_t)l * 128 * 128,
            nb1 + l * HD, nb2 + l * HD, lng + l * HD, lnb + l * HD, h, hh);
    }
    int RPB = (N + 255) / 256;
    k_pool1<<<256, 256, 0, stream>>>(h, part, N, RPB);
    k_head<<<1, 128, 0, stream>>>(part, 256, N, hw1, hb1, hw2, hb2, (float*)d_out);
}

// Round 18
// 828.807 us; speedup vs baseline: 1.0908x; 1.0616x over previous
//
#include <hip/hip_runtime.h>
#include <cstdint>
#include <cstddef>

#define HD 128
#define NLAYER 4
#define EINDIM 385

typedef _Float16 f16x8 __attribute__((ext_vector_type(8)));
typedef _Float16 f16x4 __attribute__((ext_vector_type(4)));
typedef float f32x4 __attribute__((ext_vector_type(4)));

// fast silu: v_mul+v_exp+v_add+v_rcp+v_mul (no IEEE divide)
__device__ __forceinline__ float silu_f(float x) {
    float e = __expf(-x);
    return x * __builtin_amdgcn_rcpf(1.f + e);
}

// LDS-only barrier: does NOT drain vmcnt -> prefetch loads stay in flight
__device__ __forceinline__ void lds_barrier() {
    asm volatile("s_waitcnt lgkmcnt(0)" ::: "memory");
    __builtin_amdgcn_s_barrier();
}

// ---------------- init: lam_vec + folded edge bias c1 (fp32 + fp16) ----------------
__global__ __launch_bounds__(128) void k_init(const float* __restrict__ lam_p,
                                              const float* __restrict__ lam_w,
                                              const float* __restrict__ lam_b,
                                              const float* __restrict__ edge_w1,
                                              const float* __restrict__ edge_b1,
                                              float* __restrict__ lam_vec,
                                              float* __restrict__ c1,
                                              _Float16* __restrict__ c1h) {
    __shared__ float sl[HD];
    const int j = threadIdx.x;   // 0..127
    const int l = blockIdx.x;    // 0..NLAYER-1
    float lam = lam_p[0];
    float v = lam * lam_w[j] + lam_b[j];
    sl[j] = v;
    if (l == 0) lam_vec[j] = v;
    __syncthreads();
    float acc = edge_b1[l * HD + j];
    const float* w = edge_w1 + ((size_t)l * EINDIM + 257) * HD + j;
#pragma unroll 8
    for (int k = 0; k < HD; k++) acc = fmaf(sl[k], w[(size_t)k * HD], acc);
    c1[l * HD + j] = acc;
    c1h[l * HD + j] = (_Float16)acc;
}

// ---------------- prep: transpose weights to [col][k] fp16, extract dist row ----------------
__global__ void k_prep(const float* __restrict__ ew1, const float* __restrict__ ew2,
                       const float* __restrict__ nw1, const float* __restrict__ nw2,
                       _Float16* __restrict__ W1te, _Float16* __restrict__ W2te,
                       _Float16* __restrict__ W1tn, _Float16* __restrict__ W2tn,
                       float* __restrict__ wd, _Float16* __restrict__ wdh) {
    int t = blockIdx.x * 256 + threadIdx.x;
    if (t < NLAYER * 128 * 256) {
        int l = t >> 15, r = t & 32767, j = r >> 8, k = r & 255;
        W1te[t] = (_Float16)ew1[((size_t)l * EINDIM + k) * HD + j];
        return;
    }
    t -= NLAYER * 128 * 256;
    if (t < NLAYER * 128 * 256) {
        int l = t >> 15, r = t & 32767, j = r >> 8, k = r & 255;
        W1tn[t] = (_Float16)nw1[((size_t)l * 256 + k) * HD + j];
        return;
    }
    t -= NLAYER * 128 * 256;
    if (t < NLAYER * 128 * 128) {
        int l = t >> 14, r = t & 16383, j = r >> 7, k = r & 127;
        W2te[t] = (_Float16)ew2[((size_t)l * 128 + k) * HD + j];
        return;
    }
    t -= NLAYER * 128 * 128;
    if (t < NLAYER * 128 * 128) {
        int l = t >> 14, r = t & 16383, j = r >> 7, k = r & 127;
        W2tn[t] = (_Float16)nw2[((size_t)l * 128 + k) * HD + j];
        return;
    }
    t -= NLAYER * 128 * 128;
    if (t < NLAYER * 128) {
        int l = t >> 7, j = t & 127;
        float v = ew1[((size_t)l * EINDIM + 256) * HD + j];
        wd[t] = v;
        wdh[t] = (_Float16)v;
    }
}

// ---------------- h0 = atom_embed[z] + lam_vec (fp16 only) ----------------
__global__ void k_embed(const int* __restrict__ z,
                        const float* __restrict__ atom_embed,
                        const float* __restrict__ lam_vec,
                        _Float16* __restrict__ hh, int n4) {
    int i = blockIdx.x * 256 + threadIdx.x;
    if (i >= n4) return;
    int n = i >> 5, q = i & 31;
    int a = z[n];
    float4 e = *(const float4*)&atom_embed[(size_t)a * HD + q * 4];
    float4 lv = *(const float4*)&lam_vec[q * 4];
    e.x += lv.x; e.y += lv.y; e.z += lv.z; e.w += lv.w;
    f16x4 hv;
    hv[0] = (_Float16)e.x; hv[1] = (_Float16)e.y;
    hv[2] = (_Float16)e.z; hv[3] = (_Float16)e.w;
    *(f16x4*)&hh[(size_t)n * HD + q * 4] = hv;
}

// ---------------- generic zero ----------------
__global__ void k_zero(float4* __restrict__ p, int n4) {
    for (int i = blockIdx.x * 256 + threadIdx.x; i < n4; i += gridDim.x * 256)
        p[i] = make_float4(0.f, 0.f, 0.f, 0.f);
}

// ---------------- counting sort: histogram ----------------
__global__ void k_hist(const int* __restrict__ ei, int* __restrict__ deg, int E) {
    int e = blockIdx.x * 256 + threadIdx.x;
    if (e < E) atomicAdd(&deg[ei[e]], 1);
}

// ---------------- counting sort: single-block scan deg -> cursor ----------------
__global__ __launch_bounds__(1024) void k_scan(const int* __restrict__ deg,
                                               int* __restrict__ cursor, int N) {
    __shared__ int part[1024];
    int t = threadIdx.x;
    int chunk = (N + 1023) >> 10;
    int s0 = t * chunk, s1 = s0 + chunk;
    if (s1 > N) s1 = N;
    int s = 0;
    for (int i = s0; i < s1; i++) s += deg[i];
    part[t] = s;
    __syncthreads();
    for (int d = 1; d < 1024; d <<= 1) {
        int v = (t >= d) ? part[t - d] : 0;
        __syncthreads();
        part[t] += v;
        __syncthreads();
    }
    int base = (t == 0) ? 0 : part[t - 1];
    for (int i = s0; i < s1; i++) {
        cursor[i] = base;
        base += deg[i];
    }
}

// ---------------- counting sort: scatter permutation ----------------
__global__ void k_scatter(const int* __restrict__ ei, int* __restrict__ cursor,
                          int* __restrict__ perm, int E) {
    int e = blockIdx.x * 256 + threadIdx.x;
    if (e < E) {
        int p = atomicAdd(&cursor[ei[e]], 1);
        perm[p] = e;
    }
}

// ---------------- apply perm: rowS/colS/distS (sorted by row) ----------------
__global__ void k_apply(const int* __restrict__ perm, const int* __restrict__ ei,
                        const float* __restrict__ pos,
                        int* __restrict__ rowS, int* __restrict__ colS,
                        float* __restrict__ distS, int E, int Epad) {
    int i = blockIdx.x * 256 + threadIdx.x;
    if (i >= Epad) return;
    if (i < E) {
        int e = perm[i];
        int r = ei[e], c = ei[E + e];
        rowS[i] = r; colS[i] = c;
        float dx = pos[r * 3 + 0] - pos[c * 3 + 0];
        float dy = pos[r * 3 + 1] - pos[c * 3 + 1];
        float dz = pos[r * 3 + 2] - pos[c * 3 + 2];
        distS[i] = sqrtf(dx * dx + dy * dy + dz * dz + 1e-8f);
    } else {
        rowS[i] = -1; colS[i] = 0; distS[i] = 0.f;
    }
}

// ---------------- per-tile boundary masks: bit i = rowS[i] != rowS[i+1] ----------------
__global__ void k_mask(const int* __restrict__ rowS,
                       unsigned long long* __restrict__ maskBuf, int Epad) {
    int i = blockIdx.x * 256 + threadIdx.x;
    if (i >= Epad) return;   // Epad multiple of 64: whole waves uniform
    bool pred = (i + 1 >= Epad) ? true : (rowS[i] != rowS[i + 1]);
    unsigned long long m = __ballot(pred);
    if ((i & 63) == 0) maskBuf[i >> 6] = m;
}

// =======================================================================
// per-node edge-message precompute: P = h @ W1a, Q = h @ W1b (fp16 out).
// 512 threads / 8 waves x 16 cols; dense 64-row tiles; K=128 each.
// =======================================================================
__global__ __launch_bounds__(512, 4) void k_pq(
    const _Float16* __restrict__ hh, int N,
    const _Float16* __restrict__ W1t,   // [128][256] (k<128: h_row part, k>=128: h_col part)
    _Float16* __restrict__ Ph, _Float16* __restrict__ Qh) {
    __shared__ __align__(16) _Float16 shH[64 * 136];
    const int tid = threadIdx.x;
    const int w = tid >> 6, l = tid & 63;
    const int lg = l >> 4, lr = l & 15;
    const int col = w * 16 + lr;

    f16x8 w1a[4], w1b[4];
#pragma unroll
    for (int s = 0; s < 4; s++) {
        w1a[s] = *(const f16x8*)(W1t + (size_t)col * 256 + s * 32 + lg * 8);
        w1b[s] = *(const f16x8*)(W1t + (size_t)col * 256 + 128 + s * 32 + lg * 8);
    }
    const int n0 = blockIdx.x * 64;
#pragma unroll
    for (int it = 0; it < 2; it++) {
        int flat = tid + it * 512;
        int e = flat >> 4, c = flat & 15;
        int n = n0 + e;
        f16x8 v = {};
        if (n < N) v = *(const f16x8*)(hh + (size_t)n * HD + c * 8);
        *(f16x8*)&shH[e * 136 + c * 8] = v;
    }
    __syncthreads();

    f32x4 aP[4], aQ[4];
#pragma unroll
    for (int rf = 0; rf < 4; rf++) { aP[rf] = (f32x4){0,0,0,0}; aQ[rf] = (f32x4){0,0,0,0}; }
#pragma unroll
    for (int s = 0; s < 4; s++) {
#pragma unroll
        for (int rf = 0; rf < 4; rf++) {
            f16x8 a = *(const f16x8*)&shH[(rf * 16 + lr) * 136 + s * 32 + lg * 8];
            aP[rf] = __builtin_amdgcn_mfma_f32_16x16x32_f16(a, w1a[s], aP[rf], 0, 0, 0);
            aQ[rf] = __builtin_amdgcn_mfma_f32_16x16x32_f16(a, w1b[s], aQ[rf], 0, 0, 0);
        }
    }
#pragma unroll
    for (int rf = 0; rf < 4; rf++) {
#pragma unroll
        for (int r = 0; r < 4; r++) {
            int n = n0 + rf * 16 + lg * 4 + r;
            if (n < N) {
                Ph[(size_t)n * HD + col] = (_Float16)aP[rf][r];
                Qh[(size_t)n * HD + col] = (_Float16)aQ[rf][r];
            }
        }
    }
}

// =======================================================================
// edge kernel v2: NO edge GEMM1.  m1 = silu(P[row]+Q[col]+dist*wd+c1)
// computed during staging (packed-fp16 add chain, fp32 silu); then
// GEMM2 (W2 in 16 regs/thread), ep2, mask-driven segmented reduce.
// (512,4): PROVEN no-spill point.  [unchanged from round 17]
// =======================================================================
__global__ __launch_bounds__(512, 4) void k_edge_mfma(
    const _Float16* __restrict__ Ph, const _Float16* __restrict__ Qh,
    const int* __restrict__ rowS, const int* __restrict__ colS,
    const float* __restrict__ distS,
    const unsigned long long* __restrict__ maskBuf,
    int Epad, int ntiles, int tpb,
    const _Float16* __restrict__ W2t,   // [128][128] fp16
    const _Float16* __restrict__ wdh, const _Float16* __restrict__ c1h,
    const float* __restrict__ b2,
    float* __restrict__ agg) {
    __shared__ __align__(16) _Float16 shM[64 * 136];   // m1, then final m2 (fp16)
    __shared__ int shRow2[2][64];

    const int tid = threadIdx.x;
    const int w = tid >> 6, l = tid & 63;
    const int lg = l >> 4, lr = l & 15;
    const int col = w * 16 + lr;
    const int cc = tid & 15;              // staging chunk (cols cc*8..cc*8+7)

    f16x8 w2f[4];
#pragma unroll
    for (int s = 0; s < 4; s++)
        w2f[s] = *(const f16x8*)(W2t + (size_t)col * 128 + s * 32 + lg * 8);
    const f16x8 wd8 = *(const f16x8*)(wdh + cc * 8);
    const f16x8 c18 = *(const f16x8*)(c1h + cc * 8);
    const float b2v = b2[col];

    const int t0 = blockIdx.x * tpb;
    int t1 = t0 + tpb; if (t1 > ntiles) t1 = ntiles;
    if (t0 >= t1) return;   // uniform per block

    // prefetch pipeline registers
    f16x8 vP[2], vQ[2];
    float dva[2];
    int rv = -1;

    // ---- prologue: gather tile t0 ----
    {
        const int e0 = t0 * 64;
        if (tid < 64) rv = rowS[e0 + tid];
#pragma unroll
        for (int it = 0; it < 2; it++) {
            int e = (tid + it * 512) >> 4;
            int r_ = rowS[e0 + e], q_ = colS[e0 + e];
            if (r_ < 0) r_ = 0;
            vP[it] = *(const f16x8*)(Ph + (size_t)r_ * HD + cc * 8);
            vQ[it] = *(const f16x8*)(Qh + (size_t)q_ * HD + cc * 8);
            dva[it] = distS[e0 + e];
        }
    }

    for (int t = t0; t < t1; t++) {
        const int pb = t & 1;
        const unsigned long long bmCur = maskBuf[t];
        const unsigned long long bmPrev = (t > 0) ? maskBuf[t - 1] : ~0ull;

        lds_barrier();                 // B0: prev tile's segreduce reads done

        // stage: m1 = silu(P[row]+Q[col]+dist*wd+c1) -> shM
#pragma unroll
        for (int it = 0; it < 2; it++) {
            int e = (tid + it * 512) >> 4;
            _Float16 dh = (_Float16)dva[it];
            f16x8 x = vP[it] + vQ[it] + dh * wd8 + c18;
            f16x8 mv;
#pragma unroll
            for (int j = 0; j < 8; j++)
                mv[j] = (_Float16)silu_f((float)x[j]);
            *(f16x8*)&shM[e * 136 + cc * 8] = mv;
        }
        if (tid < 64) shRow2[pb][tid] = rv;

        // prefetch tile t+1 (loads fly across the lds-only barriers)
        {
            int tn = t + 1; if (tn > ntiles - 1) tn = ntiles - 1;
            const int e0n = tn * 64;
#pragma unroll
            for (int it = 0; it < 2; it++) {
                int e = (tid + it * 512) >> 4;
                int r_ = rowS[e0n + e], q_ = colS[e0n + e];
                if (r_ < 0) r_ = 0;
                vP[it] = *(const f16x8*)(Ph + (size_t)r_ * HD + cc * 8);
                vQ[it] = *(const f16x8*)(Qh + (size_t)q_ * HD + cc * 8);
                dva[it] = distS[e0n + e];
            }
            if (tid < 64) rv = rowS[e0n + tid];
        }

        lds_barrier();                 // B1: shM(t) + shRow visible

        f32x4 acc[4];
#pragma unroll
        for (int rf = 0; rf < 4; rf++) acc[rf] = (f32x4){0.f, 0.f, 0.f, 0.f};

        // GEMM2: K=128, barrier-free (B in registers)
#pragma unroll
        for (int s = 0; s < 4; s++) {
#pragma unroll
            for (int rf = 0; rf < 4; rf++) {
                f16x8 a = *(const f16x8*)&shM[(rf * 16 + lr) * 136 + s * 32 + lg * 8];
                acc[rf] = __builtin_amdgcn_mfma_f32_16x16x32_f16(a, w2f[s], acc[rf], 0, 0, 0);
            }
        }
        lds_barrier();                 // B4: all GEMM2 reads done before overwrite

        // ep2: silu -> shM (fp16, reuse)
#pragma unroll
        for (int rf = 0; rf < 4; rf++) {
#pragma unroll
            for (int r = 0; r < 4; r++) {
                int row = rf * 16 + lg * 4 + r;
                shM[row * 136 + col] = (_Float16)silu_f(acc[rf][r] + b2v);
            }
        }
        lds_barrier();                 // B5: final m visible

        // mask-driven segmented reduction: 4 quarter-tiles x 128 cols
        {
            const int scol = tid & 127, quarter = tid >> 7;   // 0..3
            const int i0 = quarter << 4;                      // 16 rows each
            const unsigned int mh = (unsigned int)(bmCur >> i0) & 0xFFFFu;
            bool open = (quarter == 0) ? !((bmPrev >> 63) & 1ull)
                                       : !((bmCur >> (i0 - 1)) & 1ull);
            float s = 0.f;
#pragma unroll
            for (int ib = 0; ib < 4; ib++) {
                const int i = i0 + ib * 4;
                float v0 = (float)shM[(i + 0) * 136 + scol];
                float v1 = (float)shM[(i + 1) * 136 + scol];
                float v2 = (float)shM[(i + 2) * 136 + scol];
                float v3 = (float)shM[(i + 3) * 136 + scol];
#pragma unroll
                for (int q = 0; q < 4; q++) {
                    s += (q == 0) ? v0 : (q == 1) ? v1 : (q == 2) ? v2 : v3;
                    if (mh & (1u << (ib * 4 + q))) {
                        int rc = shRow2[pb][i + q];
                        if (rc >= 0) {
                            if (open) atomicAdd(&agg[(size_t)rc * HD + scol], s);
                            else      agg[(size_t)rc * HD + scol] = s;
                        }
                        s = 0.f;
                        open = false;
                    }
                }
            }
            if (!((mh >> 15) & 1u)) {
                int rc = shRow2[pb][i0 + 15];
                if (rc >= 0) atomicAdd(&agg[(size_t)rc * HD + scol], s);
            }
        }
    }
}

// =======================================================================
// node MLP via MFMA fp16 + fused residual + LayerNorm.  (256,3).
// fp32 h ELIMINATED: residual read from shA (hh already staged in LDS),
// LN writes only hh.  Staging also zeroes agg in place.
// =======================================================================
__global__ __launch_bounds__(256, 3) void k_node_mfma(
    const _Float16* __restrict__ hh_in, float* __restrict__ agg, int N,
    int ntiles, int tpb,
    const _Float16* __restrict__ W1t,   // [128][256]
    const _Float16* __restrict__ W2t,   // [128][128]
    const float* __restrict__ b1, const float* __restrict__ b2,
    const float* __restrict__ lng, const float* __restrict__ lnb,
    _Float16* __restrict__ hh_out) {
    __shared__ __align__(16) _Float16 shA[64 * 264];   // [hh | agg16]; hh part persists
    __shared__ __align__(16) _Float16 shM[64 * 136];   // silu(m1), then u+b2 (fp16)
    __shared__ float shB1[HD], shB2[HD], shG[HD], shBt[HD];

    const int tid = threadIdx.x;
    const int w = tid >> 6, l = tid & 63;
    const int lg = l >> 4, lr = l & 15;

    f16x8 w1f[2][8], w2f[2][4];
#pragma unroll
    for (int cf = 0; cf < 2; cf++) {
        const int col = w * 32 + cf * 16 + lr;
#pragma unroll
        for (int s = 0; s < 8; s++)
            w1f[cf][s] = *(const f16x8*)(W1t + (size_t)col * 256 + s * 32 + lg * 8);
#pragma unroll
        for (int s = 0; s < 4; s++)
            w2f[cf][s] = *(const f16x8*)(W2t + (size_t)col * 128 + s * 32 + lg * 8);
    }
    if (tid < 128) { shB1[tid] = b1[tid]; shB2[tid] = b2[tid]; }
    else { shG[tid - 128] = lng[tid - 128]; shBt[tid - 128] = lnb[tid - 128]; }
    __syncthreads();

    int t1 = blockIdx.x * tpb + tpb;
    if (t1 > ntiles) t1 = ntiles;
    for (int t = blockIdx.x * tpb; t < t1; t++) {
        const int n0 = t * 64;

        // stage A: [hh[n] | fp16(agg[n])]; zero agg in place after reading
#pragma unroll
        for (int it = 0; it < 8; it++) {
            int flat = tid + it * 256;
            int e = flat >> 5, c = flat & 31;
            int n = n0 + e;
            f16x8 v = {};
            if (n < N) {
                if (c < 16) {
                    v = *(const f16x8*)(hh_in + (size_t)n * HD + c * 8);
                } else {
                    float* s = agg + (size_t)n * HD + (c - 16) * 8;
                    float4 v0 = *(const float4*)s;
                    float4 v1 = *(const float4*)(s + 4);
                    v[0] = (_Float16)v0.x; v[1] = (_Float16)v0.y;
                    v[2] = (_Float16)v0.z; v[3] = (_Float16)v0.w;
                    v[4] = (_Float16)v1.x; v[5] = (_Float16)v1.y;
                    v[6] = (_Float16)v1.z; v[7] = (_Float16)v1.w;
                    float4 z4 = make_float4(0.f, 0.f, 0.f, 0.f);
                    *(float4*)s = z4;
                    *(float4*)(s + 4) = z4;
                }
            }
            *(f16x8*)&shA[e * 264 + c * 8] = v;
        }
        lds_barrier();                 // B1

        f32x4 acc[4][2];
#pragma unroll
        for (int rf = 0; rf < 4; rf++)
#pragma unroll
            for (int cf = 0; cf < 2; cf++) acc[rf][cf] = (f32x4){0.f, 0.f, 0.f, 0.f};

#pragma unroll
        for (int s = 0; s < 8; s++) {
#pragma unroll
            for (int rf = 0; rf < 4; rf++) {
                f16x8 a = *(const f16x8*)&shA[(rf * 16 + lr) * 264 + s * 32 + lg * 8];
                acc[rf][0] = __builtin_amdgcn_mfma_f32_16x16x32_f16(a, w1f[0][s], acc[rf][0], 0, 0, 0);
                acc[rf][1] = __builtin_amdgcn_mfma_f32_16x16x32_f16(a, w1f[1][s], acc[rf][1], 0, 0, 0);
            }
        }
#pragma unroll
        for (int rf = 0; rf < 4; rf++)
#pragma unroll
            for (int cf = 0; cf < 2; cf++) {
                const int col = w * 32 + cf * 16 + lr;
#pragma unroll
                for (int r = 0; r < 4; r++) {
                    int row = rf * 16 + lg * 4 + r;
                    shM[row * 136 + col] = (_Float16)silu_f(acc[rf][cf][r] + shB1[col]);
                }
            }
        lds_barrier();                 // B3

        f32x4 acc2[4][2];
#pragma unroll
        for (int rf = 0; rf < 4; rf++)
#pragma unroll
            for (int cf = 0; cf < 2; cf++) acc2[rf][cf] = (f32x4){0.f, 0.f, 0.f, 0.f};

#pragma unroll
        for (int s = 0; s < 4; s++) {
#pragma unroll
            for (int rf = 0; rf < 4; rf++) {
                f16x8 a = *(const f16x8*)&shM[(rf * 16 + lr) * 136 + s * 32 + lg * 8];
                acc2[rf][0] = __builtin_amdgcn_mfma_f32_16x16x32_f16(a, w2f[0][s], acc2[rf][0], 0, 0, 0);
                acc2[rf][1] = __builtin_amdgcn_mfma_f32_16x16x32_f16(a, w2f[1][s], acc2[rf][1], 0, 0, 0);
            }
        }
        lds_barrier();                 // B4

        // epilogue: u + b2 -> shM (fp16, reuse)
#pragma unroll
        for (int rf = 0; rf < 4; rf++)
#pragma unroll
            for (int cf = 0; cf < 2; cf++) {
                const int col = w * 32 + cf * 16 + lr;
#pragma unroll
                for (int r = 0; r < 4; r++) {
                    int row = rf * 16 + lg * 4 + r;
                    shM[row * 136 + col] = (_Float16)(acc2[rf][cf][r] + shB2[col]);
                }
            }
        lds_barrier();                 // B5

        // fused residual + LayerNorm: 4 threads per row, 32 cols each.
        // residual comes from shA (hh staged in LDS) -- no global h.
        {
            int row = tid >> 2, q = tid & 3, n = n0 + row;
            float s = 0.f, ss = 0.f;
            if (n < N) {
#pragma unroll
                for (int j = 0; j < 8; j++) {
                    int cb = q * 32 + j * 4;
                    f16x4 hv = *(const f16x4*)&shA[row * 264 + cb];
                    f16x4 uv = *(const f16x4*)&shM[row * 136 + cb];
                    float x0 = (float)hv[0] + (float)uv[0];
                    float x1 = (float)hv[1] + (float)uv[1];
                    float x2 = (float)hv[2] + (float)uv[2];
                    float x3 = (float)hv[3] + (float)uv[3];
                    s += x0 + x1 + x2 + x3;
                    ss += x0 * x0 + x1 * x1 + x2 * x2 + x3 * x3;
                }
            }
            s += __shfl_xor(s, 1);  s += __shfl_xor(s, 2);
            ss += __shfl_xor(ss, 1); ss += __shfl_xor(ss, 2);
            float mean = s * (1.f / 128.f);
            float var = ss * (1.f / 128.f) - mean * mean;
            float rstd = rsqrtf(var + 1e-5f);
            if (n < N) {
#pragma unroll
                for (int j = 0; j < 8; j++) {
                    int cb = q * 32 + j * 4;
                    f16x4 hv = *(const f16x4*)&shA[row * 264 + cb];
                    f16x4 uv = *(const f16x4*)&shM[row * 136 + cb];
                    f16x4 yh;
#pragma unroll
                    for (int k = 0; k < 4; k++) {
                        float x = (float)hv[k] + (float)uv[k];
                        yh[k] = (_Float16)((x - mean) * rstd * shG[cb + k] + shBt[cb + k]);
                    }
                    *(f16x4*)&hh_out[(size_t)n * HD + cb] = yh;
                }
            }
        }
    }
}

// ---------------- pooling stage 1 (fp16 input) ----------------
__global__ __launch_bounds__(256) void k_pool1(const _Float16* __restrict__ hh,
                                               float* __restrict__ partial,
                                               int N, int RPB) {
    int bk = blockIdx.x, t = threadIdx.x;
    int j = t & 127, half = t >> 7;
    float s = 0.f;
    int rend = (bk + 1) * RPB; if (rend > N) rend = N;
    for (int r = bk * RPB + half; r < rend; r += 2) s += (float)hh[(size_t)r * HD + j];
    __shared__ float sh[256];
    sh[t] = s;
    __syncthreads();
    if (t < 128) partial[bk * HD + j] = sh[t] + sh[t + 128];
}

// ---------------- pooling stage 2 + head MLP ----------------
__global__ __launch_bounds__(128) void k_head(const float* __restrict__ partial,
                                              int nPart, int N,
                                              const float* __restrict__ hw1,
                                              const float* __restrict__ hb1,
                                              const float* __restrict__ hw2,
                                              const float* __restrict__ hb2,
                                              float* __restrict__ out) {
    __shared__ float pooled[HD];
    __shared__ float t1[HD];
    int j = threadIdx.x;
    double s = 0.0;
    for (int bk = 0; bk < nPart; bk++) s += (double)partial[bk * HD + j];
    pooled[j] = (float)(s / (double)N);
    __syncthreads();
    float acc = hb1[j];
    for (int k = 0; k < HD; k++) acc = fmaf(pooled[k], hw1[k * HD + j], acc);
    t1[j] = silu_f(acc) * hw2[j];
    __syncthreads();
    if (j < 64) t1[j] += t1[j + 64];
    __syncthreads();
    if (j < 64) {
        float v = t1[j];
#pragma unroll
        for (int o = 32; o > 0; o >>= 1) v += __shfl_xor(v, o);
        if (j == 0) out[0] = v + hb2[0];
    }
}

extern "C" void kernel_launch(void* const* d_in, const int* in_sizes, int n_in,
                              void* d_out, int out_size, void* d_ws, size_t ws_size,
                              hipStream_t stream) {
    const int* z      = (const int*)d_in[0];
    const float* pos  = (const float*)d_in[1];
    const int* ei     = (const int*)d_in[2];
    const float* lam  = (const float*)d_in[3];
    const float* aemb = (const float*)d_in[4];
    const float* lamw = (const float*)d_in[5];
    const float* lamb = (const float*)d_in[6];
    const float* ew1  = (const float*)d_in[7];
    const float* eb1  = (const float*)d_in[8];
    const float* ew2  = (const float*)d_in[9];
    const float* eb2  = (const float*)d_in[10];
    const float* nw1  = (const float*)d_in[11];
    const float* nb1  = (const float*)d_in[12];
    const float* nw2  = (const float*)d_in[13];
    const float* nb2  = (const float*)d_in[14];
    const float* lng  = (const float*)d_in[15];
    const float* lnb  = (const float*)d_in[16];
    const float* hw1  = (const float*)d_in[17];
    const float* hb1  = (const float*)d_in[18];
    const float* hw2  = (const float*)d_in[19];
    const float* hb2  = (const float*)d_in[20];

    const int N = in_sizes[0];
    const int E = in_sizes[2] / 2;
    const int etiles = (E + 63) / 64;
    const int Epad = etiles * 64;
    const int ntilesN = (N + 63) / 64;

    char* ws = (char*)d_ws;
    size_t off = 0;
    auto alloc = [&](size_t bytes) { void* p = ws + off; off += (bytes + 255) & ~(size_t)255; return p; };
    float* agg      = (float*)alloc((size_t)N * HD * 4);
    _Float16* hh    = (_Float16*)alloc((size_t)N * HD * 2);
    _Float16* Ph    = (_Float16*)alloc((size_t)N * HD * 2);
    _Float16* Qh    = (_Float16*)alloc((size_t)N * HD * 2);
    int* deg        = (int*)alloc((size_t)N * 4);
    int* cursor     = (int*)alloc((size_t)N * 4);
    int* perm       = (int*)alloc((size_t)E * 4);
    int* rowS       = (int*)alloc((size_t)Epad * 4);
    int* colS       = (int*)alloc((size_t)Epad * 4);
    float* distS    = (float*)alloc((size_t)Epad * 4);
    unsigned long long* maskBuf = (unsigned long long*)alloc((size_t)etiles * 8);
    float* lamv     = (float*)alloc(HD * 4);
    float* c1       = (float*)alloc(NLAYER * HD * 4);
    _Float16* c1h   = (_Float16*)alloc(NLAYER * HD * 2);
    float* wd       = (float*)alloc(NLAYER * HD * 4);
    _Float16* wdh   = (_Float16*)alloc(NLAYER * HD * 2);
    float* part     = (float*)alloc(256 * HD * 4);
    _Float16* W1te  = (_Float16*)alloc((size_t)NLAYER * 128 * 256 * 2);
    _Float16* W1tn  = (_Float16*)alloc((size_t)NLAYER * 128 * 256 * 2);
    _Float16* W2te  = (_Float16*)alloc((size_t)NLAYER * 128 * 128 * 2);
    _Float16* W2tn  = (_Float16*)alloc((size_t)NLAYER * 128 * 128 * 2);

    // --- setup (once per launch) ---
    k_init<<<NLAYER, 128, 0, stream>>>(lam, lamw, lamb, ew1, eb1, lamv, c1, c1h);
    int prepTot = NLAYER * 128 * 256 * 2 + NLAYER * 128 * 128 * 2 + NLAYER * 128;
    k_prep<<<(prepTot + 255) / 256, 256, 0, stream>>>(ew1, ew2, nw1, nw2,
                                                      W1te, W2te, W1tn, W2tn, wd, wdh);
    int n4 = N * 32;
    k_embed<<<(n4 + 255) / 256, 256, 0, stream>>>(z, aemb, lamv, hh, n4);

    // --- counting sort of edges by row + boundary masks ---
    k_zero<<<64, 256, 0, stream>>>((float4*)deg, (N + 3) / 4);
    k_hist<<<(E + 255) / 256, 256, 0, stream>>>(ei, deg, E);
    k_scan<<<1, 1024, 0, stream>>>(deg, cursor, N);
    k_scatter<<<(E + 255) / 256, 256, 0, stream>>>(ei, cursor, perm, E);
    k_apply<<<(Epad + 255) / 256, 256, 0, stream>>>(perm, ei, pos, rowS, colS, distS, E, Epad);
    k_mask<<<(Epad + 255) / 256, 256, 0, stream>>>(rowS, maskBuf, Epad);

    // agg zero once (layer 0); k_node re-zeroes in place for subsequent layers
    int zero4 = N * (HD / 4);
    k_zero<<<2048, 256, 0, stream>>>((float4*)agg, zero4);

    // --- layer loop ---
    const int egrid = (etiles < 512) ? etiles : 512;   // 2 blocks/CU at (512,4), proven
    const int etpb = (etiles + egrid - 1) / egrid;
    const int ngrid = (ntilesN + 1) / 2;               // tpb=2
    for (int l = 0; l < NLAYER; l++) {
        k_pq<<<ntilesN, 512, 0, stream>>>(hh, N, W1te + (size_t)l * 128 * 256, Ph, Qh);
        k_edge_mfma<<<egrid, 512, 0, stream>>>(Ph, Qh, rowS, colS, distS, maskBuf,
            Epad, etiles, etpb,
            W2te + (size_t)l * 128 * 128, wdh + l * HD, c1h + l * HD,
            eb2 + l * HD, agg);
        k_node_mfma<<<ngrid, 256, 0, stream>>>(hh, agg, N, ntilesN, 2,
            W1tn + (size_t)l * 128 * 256, W2tn + (size_t)l * 128 * 128,
            nb1 + l * HD, nb2 + l * HD, lng + l * HD, lnb + l * HD, hh);
    }
    int RPB = (N + 255) / 256;
    k_pool1<<<256, 256, 0, stream>>>(hh, part, N, RPB);
    k_head<<<1, 128, 0, stream>>>(part, 256, N, hw1, hb1, hw2, hb2, (float*)d_out);
}